// Round 7
// baseline (568.208 us; speedup 1.0000x reference)
//
#include <hip/hip_runtime.h>
#include <hip/hip_bf16.h>

typedef _Float16 h8 __attribute__((ext_vector_type(8)));
typedef _Float16 h4v __attribute__((ext_vector_type(4)));
typedef float f4 __attribute__((ext_vector_type(4)));

#define T_ 4
#define B_ 8
#define N_ 512
#define C_ 512
#define H_ 8
#define D_ 64
#define BNR 4096
#define EPSf 1e-5f
#define F16_MIN_NORM 6.1035156e-05f
#define INV4096 0.000244140625f

// ---- x -> (h1 + 2^-12 * h2) f16 split, packed MFMA-fragment-linear ----
// A1p/A2p[rt][t][ks][lane][8]: lane l holds x[t][rt*16 + (l&15)][ks*32 + (l>>4)*8 ..+8]
__global__ __launch_bounds__(256)
void split_pack_x(const float* __restrict__ in, _Float16* __restrict__ h1,
                  _Float16* __restrict__ h2)
{
    const int gid = blockIdx.x * 256 + threadIdx.x;    // 1048576 h8-groups
    const int lane = gid & 63;
    const int ks = (gid >> 6) & 15;
    const int t = (gid >> 10) & 3;
    const int rt = gid >> 12;
    const int row = rt * 16 + (lane & 15);
    const size_t src = ((size_t)t * BNR + row) * C_ + ks * 32 + (lane >> 4) * 8;
    const float4 x0 = *reinterpret_cast<const float4*>(in + src);
    const float4 x1 = *reinterpret_cast<const float4*>(in + src + 4);
    h8 a, b;
    #pragma unroll
    for (int j = 0; j < 8; ++j) {
        const float xv = (j < 4) ? (&x0.x)[j] : (&x1.x)[j - 4];
        const float hi = (fabsf(xv) >= F16_MIN_NORM) ? xv : 0.0f;  // no subnormal x1
        const _Float16 h = (_Float16)hi;
        const float r = (xv - (float)h) * 4096.0f;                 // normal-range residual
        a[j] = h; b[j] = (_Float16)r;
    }
    *reinterpret_cast<h8*>(h1 + (size_t)gid * 8) = a;
    *reinterpret_cast<h8*>(h2 + (size_t)gid * 8) = b;
}

// ---- W -> split + MFMA-fragment-linear pack, all 4 branches in one launch ----
__device__ __forceinline__
void pack_w_one(const float* __restrict__ W, _Float16* __restrict__ Wp1,
                _Float16* __restrict__ Wp2, int gid)
{
    const int lane = gid & 63;
    const int ni = (gid >> 6) & 3;
    const int ks = (gid >> 8) & 15;
    const int ct = gid >> 12;
    const int col = ct * 64 + ni * 16 + (lane & 15);
    const int k = ks * 32 + (lane >> 4) * 8;
    const float* src = W + (size_t)col * C_ + k;
    h8 a, b;
    #pragma unroll
    for (int j = 0; j < 8; ++j) {
        const float xv = src[j];
        const float hi = (fabsf(xv) >= F16_MIN_NORM) ? xv : 0.0f;
        const _Float16 h = (_Float16)hi;
        const float r = (xv - (float)h) * 4096.0f;
        a[j] = h; b[j] = (_Float16)r;
    }
    *reinterpret_cast<h8*>(Wp1 + (size_t)gid * 8) = a;
    *reinterpret_cast<h8*>(Wp2 + (size_t)gid * 8) = b;
}

__global__ __launch_bounds__(256)
void pack_w_all(const float* __restrict__ Wq, const float* __restrict__ Wk,
                const float* __restrict__ Wv, const float* __restrict__ Wp,
                _Float16* q1, _Float16* q2, _Float16* k1, _Float16* k2,
                _Float16* v1, _Float16* v2, _Float16* p1, _Float16* p2)
{
    const int g = blockIdx.x * 256 + threadIdx.x;     // 131072
    const int br = g >> 15;                            // uniform per block
    const int gid = g & 32767;
    if (br == 0)      pack_w_one(Wq, q1, q2, gid);
    else if (br == 1) pack_w_one(Wk, k1, k2, gid);
    else if (br == 2) pack_w_one(Wv, v1, v2, gid);
    else              pack_w_one(Wp, p1, p2, gid);
}

// ---- fused q/k/v MFMA GEMM + BN + LIF: A-fragments loaded ONCE, 3 W streams ----
// 1 wave/SIMD (big unified VGPR+AGPR budget: 3x(accA,accB) = 384 acc regs).
// Per k-step: 8 A-loads + 24 W-loads + 144 MFMA -> MFMA-bound, ILP hides TA.
__global__ __launch_bounds__(256, 1)
void fused_qkv(const _Float16* __restrict__ A1p, const _Float16* __restrict__ A2p,
               const _Float16* __restrict__ Wq1, const _Float16* __restrict__ Wq2,
               const _Float16* __restrict__ Wk1, const _Float16* __restrict__ Wk2,
               const _Float16* __restrict__ Wv1, const _Float16* __restrict__ Wv2,
               const float* __restrict__ biq, const float* __restrict__ gaq,
               const float* __restrict__ beq, const float* __restrict__ meq,
               const float* __restrict__ rvq,
               const float* __restrict__ bik, const float* __restrict__ gak,
               const float* __restrict__ bek, const float* __restrict__ mek,
               const float* __restrict__ rvk,
               const float* __restrict__ biv, const float* __restrict__ gav,
               const float* __restrict__ bev, const float* __restrict__ mev,
               const float* __restrict__ rvv,
               __hip_bfloat16* __restrict__ oq, __hip_bfloat16* __restrict__ ok,
               __hip_bfloat16* __restrict__ ov)
{
    const int id = blockIdx.x;
    const int bt = (id & 7) * 8 + ((id >> 3) & 7);      // XCD-aware swizzle
    const int ct = id >> 6;
    const int wv = threadIdx.x >> 6, lane = threadIdx.x & 63;
    const int rt = bt * 4 + wv;
    const int row0 = bt * 64, col0 = ct * 64;
    const int lr = lane & 15, lk = lane >> 4;

    f4 qA[4][4], qB[4][4], kA[4][4], kB[4][4], vA[4][4], vB[4][4];
    #pragma unroll
    for (int t = 0; t < 4; ++t)
        #pragma unroll
        for (int ni = 0; ni < 4; ++ni) {
            qA[t][ni] = (f4)0.0f; qB[t][ni] = (f4)0.0f;
            kA[t][ni] = (f4)0.0f; kB[t][ni] = (f4)0.0f;
            vA[t][ni] = (f4)0.0f; vB[t][ni] = (f4)0.0f;
        }

    const _Float16* aB1 = A1p + (size_t)rt * 32768 + lane * 8;
    const _Float16* aB2 = A2p + (size_t)rt * 32768 + lane * 8;
    const size_t wbase = (size_t)ct * 32768 + lane * 8;
    const _Float16* q1B = Wq1 + wbase; const _Float16* q2B = Wq2 + wbase;
    const _Float16* k1B = Wk1 + wbase; const _Float16* k2B = Wk2 + wbase;
    const _Float16* v1B = Wv1 + wbase; const _Float16* v2B = Wv2 + wbase;

    auto loadW = [&](const _Float16* b1, const _Float16* b2, int ks,
                     h8 (&w1f)[4], h8 (&w2f)[4]) {
        #pragma unroll
        for (int ni = 0; ni < 4; ++ni) {
            w1f[ni] = *reinterpret_cast<const h8*>(b1 + (ks * 4 + ni) * 512);
            w2f[ni] = *reinterpret_cast<const h8*>(b2 + (ks * 4 + ni) * 512);
        }
    };
    auto branch = [&](f4 (&A)[4][4], f4 (&Bc)[4][4], const h8 (&w1f)[4],
                      const h8 (&w2f)[4], const h8 (&a1)[4], const h8 (&a2)[4]) {
        #pragma unroll
        for (int ni = 0; ni < 4; ++ni)
            #pragma unroll
            for (int t = 0; t < 4; ++t) {
                A[t][ni]  = __builtin_amdgcn_mfma_f32_16x16x32_f16(a1[t], w1f[ni], A[t][ni], 0, 0, 0);
                Bc[t][ni] = __builtin_amdgcn_mfma_f32_16x16x32_f16(a1[t], w2f[ni], Bc[t][ni], 0, 0, 0);
                Bc[t][ni] = __builtin_amdgcn_mfma_f32_16x16x32_f16(a2[t], w1f[ni], Bc[t][ni], 0, 0, 0);
            }
    };

    #pragma unroll 2
    for (int ks = 0; ks < 16; ++ks) {
        h8 a1[4], a2[4];
        #pragma unroll
        for (int t = 0; t < 4; ++t) {
            a1[t] = *reinterpret_cast<const h8*>(aB1 + (t * 16 + ks) * 512);
            a2[t] = *reinterpret_cast<const h8*>(aB2 + (t * 16 + ks) * 512);
        }
        h8 wq1f[4], wq2f[4], wk1f[4], wk2f[4], wv1f[4], wv2f[4];
        loadW(q1B, q2B, ks, wq1f, wq2f);
        loadW(k1B, k2B, ks, wk1f, wk2f);     // flies under q-MFMAs
        branch(qA, qB, wq1f, wq2f, a1, a2);
        loadW(v1B, v2B, ks, wv1f, wv2f);     // flies under k-MFMAs
        branch(kA, kB, wk1f, wk2f, a1, a2);
        branch(vA, vB, wv1f, wv2f, a1, a2);
    }

    // ---- in-register BN + LIF epilogue, one pass per branch ----
    auto epi = [&](f4 (&A)[4][4], f4 (&Bc)[4][4], const float* bias, const float* gam,
                   const float* bet, const float* mea, const float* rva,
                   __hip_bfloat16* out) {
        #pragma unroll
        for (int ni = 0; ni < 4; ++ni) {
            const int c = col0 + ni * 16 + lr;
            const float sc = gam[c] * (1.0f / sqrtf(rva[c] + EPSf));
            const float bi = bias[c], mn = mea[c], be = bet[c];
            #pragma unroll
            for (int r = 0; r < 4; ++r) {
                const int bn = row0 + wv * 16 + lk * 4 + r;  // C/D: row=(l>>4)*4+reg
                float vm = 0.0f;
                #pragma unroll
                for (int t = 0; t < 4; ++t) {
                    const float res = A[t][ni][r] + INV4096 * Bc[t][ni][r];
                    const float y = ((res + bi) - mn) * sc + be;
                    vm = vm + (y - vm) * 0.5f;
                    const float s = (vm >= 1.0f) ? 1.0f : 0.0f;
                    vm = (s != 0.0f) ? 0.0f : vm;
                    const int b = bn >> 9, n = bn & 511;
                    out[((((size_t)t * B_ + b) * H_ + ct) * N_ + n) * D_ + ni * 16 + lr] =
                        __float2bfloat16(s);
                }
            }
        }
    };
    epi(qA, qB, biq, gaq, beq, meq, rvq, oq);
    epi(kA, kB, bik, gak, bek, mek, rvk, ok);
    epi(vA, vB, biv, gav, bev, mev, rvv, ov);
}

// ---- MODE1: p-GEMM (A = exact f16 spikes, packed), W split, out fp32 ----
__global__ __launch_bounds__(256, 2)
void mfma_gemm_p(const _Float16* __restrict__ A1p,
                 const _Float16* __restrict__ Wp1, const _Float16* __restrict__ Wp2,
                 const float* __restrict__ bias, const float* __restrict__ gam,
                 const float* __restrict__ bet, const float* __restrict__ mea,
                 const float* __restrict__ rva, float* __restrict__ out_plain)
{
    const int id = blockIdx.x;
    const int bt = (id & 7) * 8 + ((id >> 3) & 7);
    const int ct = id >> 6;
    const int wv = threadIdx.x >> 6, lane = threadIdx.x & 63;
    const int rt = bt * 4 + wv;
    const int row0 = bt * 64, col0 = ct * 64;
    const int lr = lane & 15, lk = lane >> 4;

    f4 accA[4][4], accB[4][4];
    #pragma unroll
    for (int t = 0; t < 4; ++t)
        #pragma unroll
        for (int ni = 0; ni < 4; ++ni) { accA[t][ni] = (f4)0.0f; accB[t][ni] = (f4)0.0f; }

    const _Float16* aB1 = A1p + (size_t)rt * 32768 + lane * 8;
    const _Float16* wB1 = Wp1 + (size_t)ct * 32768 + lane * 8;
    const _Float16* wB2 = Wp2 + (size_t)ct * 32768 + lane * 8;

    #pragma unroll 2
    for (int ks = 0; ks < 16; ++ks) {
        h8 wf1[4], wf2[4];
        #pragma unroll
        for (int ni = 0; ni < 4; ++ni) {
            wf1[ni] = *reinterpret_cast<const h8*>(wB1 + (ks * 4 + ni) * 512);
            wf2[ni] = *reinterpret_cast<const h8*>(wB2 + (ks * 4 + ni) * 512);
        }
        #pragma unroll
        for (int t = 0; t < 4; ++t) {
            const h8 a1 = *reinterpret_cast<const h8*>(aB1 + (t * 16 + ks) * 512);
            #pragma unroll
            for (int ni = 0; ni < 4; ++ni) {
                accA[t][ni] = __builtin_amdgcn_mfma_f32_16x16x32_f16(a1, wf1[ni], accA[t][ni], 0, 0, 0);
                accB[t][ni] = __builtin_amdgcn_mfma_f32_16x16x32_f16(a1, wf2[ni], accB[t][ni], 0, 0, 0);
            }
        }
    }

    #pragma unroll
    for (int ni = 0; ni < 4; ++ni) {
        const int c = col0 + ni * 16 + lr;
        const float sc = gam[c] * (1.0f / sqrtf(rva[c] + EPSf));
        const float bi = bias[c], mn = mea[c], be = bet[c];
        #pragma unroll
        for (int r = 0; r < 4; ++r) {
            const int bn = row0 + wv * 16 + lk * 4 + r;
            float vm = 0.0f;
            #pragma unroll
            for (int t = 0; t < 4; ++t) {
                const float res = accA[t][ni][r] + INV4096 * accB[t][ni][r];
                const float y = ((res + bi) - mn) * sc + be;
                vm = vm + (y - vm) * 0.5f;
                const float s = (vm >= 1.0f) ? 1.0f : 0.0f;
                vm = (s != 0.0f) ? 0.0f : vm;
                out_plain[((size_t)t * BNR + bn) * C_ + c] = s;
            }
        }
    }
}

// ---- kv[d1][d2] = sum_n k[n,d1]*v[n,d2] per (t,b,h) ----
__global__ __launch_bounds__(256)
void ktv_kernel(const __hip_bfloat16* __restrict__ sk, const __hip_bfloat16* __restrict__ sv,
                float* __restrict__ kv)
{
    __shared__ __hip_bfloat16 kl[64][64];
    __shared__ __hip_bfloat16 vl[64][64];
    const int tbh = blockIdx.x;
    const int tid = threadIdx.x;
    const int tx = tid & 15, ty = tid >> 4;
    const size_t base = (size_t)tbh * N_ * D_;
    float acc[4][4] = {};
    for (int n0 = 0; n0 < N_; n0 += 64) {
        __syncthreads();
        #pragma unroll
        for (int p = 0; p < 2; ++p) {
            const int idx = tid + p * 256;
            const int r = idx >> 3, c8 = (idx & 7) * 8;
            *reinterpret_cast<float4*>(&kl[r][c8]) =
                *reinterpret_cast<const float4*>(&sk[base + (size_t)(n0 + r) * D_ + c8]);
            *reinterpret_cast<float4*>(&vl[r][c8]) =
                *reinterpret_cast<const float4*>(&sv[base + (size_t)(n0 + r) * D_ + c8]);
        }
        __syncthreads();
        for (int nn = 0; nn < 64; ++nn) {
            float a[4], b[4];
            #pragma unroll
            for (int i = 0; i < 4; ++i) a[i] = __bfloat162float(kl[nn][ty * 4 + i]);
            #pragma unroll
            for (int j = 0; j < 4; ++j) b[j] = __bfloat162float(vl[nn][tx * 4 + j]);
            #pragma unroll
            for (int i = 0; i < 4; ++i)
                #pragma unroll
                for (int j = 0; j < 4; ++j)
                    acc[i][j] = fmaf(a[i], b[j], acc[i][j]);
        }
    }
    float* out = kv + (size_t)tbh * 4096;
    #pragma unroll
    for (int i = 0; i < 4; ++i)
        #pragma unroll
        for (int j = 0; j < 4; ++j)
            out[(ty * 4 + i) * 64 + tx * 4 + j] = acc[i][j];
}

// ---- o = 0.125 * q @ kv, fused attn-LIF (vth=0.5); writes packed f16 spikes ----
__global__ __launch_bounds__(256)
void qkv_lif_kernel(const __hip_bfloat16* __restrict__ sq, const float* __restrict__ kv,
                    _Float16* __restrict__ osp)
{
    __shared__ float kvl[64][64];
    __shared__ __hip_bfloat16 ql[64][64];
    const int nt = blockIdx.x, b = blockIdx.y, h = blockIdx.z;
    const int tid = threadIdx.x;
    const int tx = tid & 15, ty = tid >> 4;
    const int n0 = nt * 64;
    float v[4][4] = {};
    for (int t = 0; t < T_; ++t) {
        const int tbh = (t * B_ + b) * H_ + h;
        __syncthreads();
        #pragma unroll
        for (int p = 0; p < 16; ++p) {
            const int idx = p * 256 + tid;
            kvl[idx >> 6][idx & 63] = kv[(size_t)tbh * 4096 + idx];
        }
        #pragma unroll
        for (int p = 0; p < 2; ++p) {
            const int idx = tid + p * 256;
            const int r = idx >> 3, c8 = (idx & 7) * 8;
            *reinterpret_cast<float4*>(&ql[r][c8]) =
                *reinterpret_cast<const float4*>(&sq[((size_t)tbh * N_ + n0 + r) * D_ + c8]);
        }
        __syncthreads();
        float acc[4][4] = {};
        for (int dd = 0; dd < 64; ++dd) {
            float a[4], bb[4];
            #pragma unroll
            for (int i = 0; i < 4; ++i) a[i] = __bfloat162float(ql[ty * 4 + i][dd]);
            #pragma unroll
            for (int j = 0; j < 4; ++j) bb[j] = kvl[dd][tx * 4 + j];
            #pragma unroll
            for (int i = 0; i < 4; ++i)
                #pragma unroll
                for (int j = 0; j < 4; ++j)
                    acc[i][j] = fmaf(a[i], bb[j], acc[i][j]);
        }
        #pragma unroll
        for (int i = 0; i < 4; ++i) {
            const int row_bn = b * N_ + n0 + ty * 4 + i;
            const int c0 = h * 64 + tx * 4;
            const int rt = row_bn >> 4, rlo = row_bn & 15;
            const int ks = c0 >> 5, lk3 = (c0 >> 3) & 3, j0 = c0 & 7;
            h4v sp;
            #pragma unroll
            for (int j = 0; j < 4; ++j) {
                const float y = 0.125f * acc[i][j];     // exact (integer counts)
                float vv = v[i][j];
                vv = vv + (y - vv) * 0.5f;
                const float s = (vv >= 0.5f) ? 1.0f : 0.0f;
                sp[j] = (_Float16)s;
                v[i][j] = (s != 0.0f) ? 0.0f : vv;
            }
            _Float16* dst = osp + ((((size_t)rt * 4 + t) * 16 + ks) * 64 + lk3 * 16 + rlo) * 8 + j0;
            *reinterpret_cast<h4v*>(dst) = sp;
        }
    }
}

extern "C" void kernel_launch(void* const* d_in, const int* in_sizes, int n_in,
                              void* d_out, int out_size, void* d_ws, size_t ws_size,
                              hipStream_t stream)
{
    const float* x = (const float*)d_in[0];
    const float *W[4], *bia[4], *gam[4], *bet[4], *mea[4], *rva[4];
    for (int br = 0; br < 4; ++br) {
        W[br]   = (const float*)d_in[1 + 6 * br + 0];
        bia[br] = (const float*)d_in[1 + 6 * br + 1];
        gam[br] = (const float*)d_in[1 + 6 * br + 2];
        bet[br] = (const float*)d_in[1 + 6 * br + 3];
        mea[br] = (const float*)d_in[1 + 6 * br + 4];
        rva[br] = (const float*)d_in[1 + 6 * br + 5];
    }
    char* ws = (char*)d_ws;
    _Float16* x1 = (_Float16*)(ws + 0);
    _Float16* x2 = (_Float16*)(ws + 16777216);
    __hip_bfloat16* sq = (__hip_bfloat16*)(ws + 33554432);
    __hip_bfloat16* sk = (__hip_bfloat16*)(ws + 50331648);
    __hip_bfloat16* sv = (__hip_bfloat16*)(ws + 67108864);
    _Float16* w1[4], *w2[4];
    for (int br = 0; br < 4; ++br) {
        w1[br] = (_Float16*)(ws + 83886080 + (size_t)br * 1048576);
        w2[br] = (_Float16*)(ws + 83886080 + (size_t)br * 1048576 + 524288);
    }
    float*    kv  = (float*)(ws + 16777216);     // aliases x2 (dead after fused_qkv)
    _Float16* osp = (_Float16*)(ws + 0);         // aliases x1 (dead after fused_qkv)

    dim3 blk(256);
    split_pack_x<<<dim3(4096), blk, 0, stream>>>(x, x1, x2);
    pack_w_all<<<dim3(512), blk, 0, stream>>>(W[0], W[1], W[2], W[3],
        w1[0], w2[0], w1[1], w2[1], w1[2], w2[2], w1[3], w2[3]);

    fused_qkv<<<dim3(512), blk, 0, stream>>>(x1, x2,
        w1[0], w2[0], w1[1], w2[1], w1[2], w2[2],
        bia[0], gam[0], bet[0], mea[0], rva[0],
        bia[1], gam[1], bet[1], mea[1], rva[1],
        bia[2], gam[2], bet[2], mea[2], rva[2],
        sq, sk, sv);

    ktv_kernel<<<dim3(T_ * B_ * H_), blk, 0, stream>>>(sk, sv, kv);
    qkv_lif_kernel<<<dim3(N_ / 64, B_, H_), blk, 0, stream>>>(sq, kv, osp);

    mfma_gemm_p<<<dim3(512), blk, 0, stream>>>(osp, w1[3], w2[3],
        bia[3], gam[3], bet[3], mea[3], rva[3], (float*)d_out);
}

// Round 8
// 187.980 us; speedup vs baseline: 3.0227x; 3.0227x over previous
//
#include <hip/hip_runtime.h>
#include <hip/hip_bf16.h>

typedef _Float16 h8 __attribute__((ext_vector_type(8)));
typedef _Float16 h4v __attribute__((ext_vector_type(4)));
typedef float f4 __attribute__((ext_vector_type(4)));

#define T_ 4
#define B_ 8
#define N_ 512
#define C_ 512
#define H_ 8
#define D_ 64
#define BNR 4096
#define EPSf 1e-5f
#define F16_MIN_NORM 6.1035156e-05f
#define INV4096 0.000244140625f

// ---- x -> (h1 + 2^-12 * h2) f16 split, packed MFMA-fragment-linear ----
// A1p/A2p[rt][t][ks][lane][8]: lane l holds x[t][rt*16 + (l&15)][ks*32 + (l>>4)*8 ..+8]
__global__ __launch_bounds__(256)
void split_pack_x(const float* __restrict__ in, _Float16* __restrict__ h1,
                  _Float16* __restrict__ h2)
{
    const int gid = blockIdx.x * 256 + threadIdx.x;    // 1048576 h8-groups
    const int lane = gid & 63;
    const int ks = (gid >> 6) & 15;
    const int t = (gid >> 10) & 3;
    const int rt = gid >> 12;
    const int row = rt * 16 + (lane & 15);
    const size_t src = ((size_t)t * BNR + row) * C_ + ks * 32 + (lane >> 4) * 8;
    const float4 x0 = *reinterpret_cast<const float4*>(in + src);
    const float4 x1 = *reinterpret_cast<const float4*>(in + src + 4);
    h8 a, b;
    #pragma unroll
    for (int j = 0; j < 8; ++j) {
        const float xv = (j < 4) ? (&x0.x)[j] : (&x1.x)[j - 4];
        const float hi = (fabsf(xv) >= F16_MIN_NORM) ? xv : 0.0f;  // no subnormal x1
        const _Float16 h = (_Float16)hi;
        const float r = (xv - (float)h) * 4096.0f;                 // normal-range residual
        a[j] = h; b[j] = (_Float16)r;
    }
    *reinterpret_cast<h8*>(h1 + (size_t)gid * 8) = a;
    *reinterpret_cast<h8*>(h2 + (size_t)gid * 8) = b;
}

// ---- W -> split + MFMA-fragment-linear pack, all 4 branches in one launch ----
__device__ __forceinline__
void pack_w_one(const float* __restrict__ W, _Float16* __restrict__ Wp1,
                _Float16* __restrict__ Wp2, int gid)
{
    const int lane = gid & 63;
    const int ni = (gid >> 6) & 3;
    const int ks = (gid >> 8) & 15;
    const int ct = gid >> 12;
    const int col = ct * 64 + ni * 16 + (lane & 15);
    const int k = ks * 32 + (lane >> 4) * 8;
    const float* src = W + (size_t)col * C_ + k;
    h8 a, b;
    #pragma unroll
    for (int j = 0; j < 8; ++j) {
        const float xv = src[j];
        const float hi = (fabsf(xv) >= F16_MIN_NORM) ? xv : 0.0f;
        const _Float16 h = (_Float16)hi;
        const float r = (xv - (float)h) * 4096.0f;
        a[j] = h; b[j] = (_Float16)r;
    }
    *reinterpret_cast<h8*>(Wp1 + (size_t)gid * 8) = a;
    *reinterpret_cast<h8*>(Wp2 + (size_t)gid * 8) = b;
}

__global__ __launch_bounds__(256)
void pack_w_all(const float* __restrict__ Wq, const float* __restrict__ Wk,
                const float* __restrict__ Wv, const float* __restrict__ Wp,
                _Float16* q1, _Float16* q2, _Float16* k1, _Float16* k2,
                _Float16* v1, _Float16* v2, _Float16* p1, _Float16* p2)
{
    const int g = blockIdx.x * 256 + threadIdx.x;     // 131072
    const int br = g >> 15;                            // uniform per block
    const int gid = g & 32767;
    if (br == 0)      pack_w_one(Wq, q1, q2, gid);
    else if (br == 1) pack_w_one(Wk, k1, k2, gid);
    else if (br == 2) pack_w_one(Wv, v1, v2, gid);
    else              pack_w_one(Wp, p1, p2, gid);
}

// ---- LDS-free MFMA GEMM (f16 split) + BN + LIF; 3 branches via blockIdx.y ----
// Block: 4 independent waves; wave w: rows [bt*64+16w,+16) x 64 cols x all 4 t.
// Fully-unrolled K-loop (straight-line): pressure-aware scheduler hoists the
// coalesced fragment loads several k-steps deep (its own software pipeline).
__global__ __launch_bounds__(256, 2)
void gemm3_bn_lif(const _Float16* __restrict__ A1p, const _Float16* __restrict__ A2p,
                  const _Float16* __restrict__ Wq1, const _Float16* __restrict__ Wq2,
                  const _Float16* __restrict__ Wk1, const _Float16* __restrict__ Wk2,
                  const _Float16* __restrict__ Wv1, const _Float16* __restrict__ Wv2,
                  const float* __restrict__ biq, const float* __restrict__ gaq,
                  const float* __restrict__ beq, const float* __restrict__ meq,
                  const float* __restrict__ rvq,
                  const float* __restrict__ bik, const float* __restrict__ gak,
                  const float* __restrict__ bek, const float* __restrict__ mek,
                  const float* __restrict__ rvk,
                  const float* __restrict__ biv, const float* __restrict__ gav,
                  const float* __restrict__ bev, const float* __restrict__ mev,
                  const float* __restrict__ rvv,
                  __hip_bfloat16* __restrict__ oq, __hip_bfloat16* __restrict__ ok,
                  __hip_bfloat16* __restrict__ ov)
{
    const int br = blockIdx.y;                          // uniform
    const _Float16* W1 = (br == 0) ? Wq1 : (br == 1) ? Wk1 : Wv1;
    const _Float16* W2 = (br == 0) ? Wq2 : (br == 1) ? Wk2 : Wv2;
    const float* bias = (br == 0) ? biq : (br == 1) ? bik : biv;
    const float* gam  = (br == 0) ? gaq : (br == 1) ? gak : gav;
    const float* bet  = (br == 0) ? beq : (br == 1) ? bek : bev;
    const float* mea  = (br == 0) ? meq : (br == 1) ? mek : mev;
    const float* rva  = (br == 0) ? rvq : (br == 1) ? rvk : rvv;
    __hip_bfloat16* out = (br == 0) ? oq : (br == 1) ? ok : ov;

    const int id = blockIdx.x;
    const int bt = (id & 7) * 8 + ((id >> 3) & 7);      // XCD-aware swizzle
    const int ct = id >> 6;
    const int wv = threadIdx.x >> 6, lane = threadIdx.x & 63;
    const int rt = bt * 4 + wv;
    const int row0 = bt * 64, col0 = ct * 64;
    const int lr = lane & 15, lk = lane >> 4;

    f4 accA[4][4], accB[4][4];                          // [t][ni]
    #pragma unroll
    for (int t = 0; t < 4; ++t)
        #pragma unroll
        for (int ni = 0; ni < 4; ++ni) { accA[t][ni] = (f4)0.0f; accB[t][ni] = (f4)0.0f; }

    const _Float16* aB1 = A1p + (size_t)rt * 32768 + lane * 8;
    const _Float16* aB2 = A2p + (size_t)rt * 32768 + lane * 8;
    const _Float16* wB1 = W1 + (size_t)ct * 32768 + lane * 8;
    const _Float16* wB2 = W2 + (size_t)ct * 32768 + lane * 8;

    #pragma unroll
    for (int ks = 0; ks < 16; ++ks) {
        h8 wf1[4], wf2[4];
        #pragma unroll
        for (int ni = 0; ni < 4; ++ni) {
            wf1[ni] = *reinterpret_cast<const h8*>(wB1 + (ks * 4 + ni) * 512);
            wf2[ni] = *reinterpret_cast<const h8*>(wB2 + (ks * 4 + ni) * 512);
        }
        #pragma unroll
        for (int t = 0; t < 4; ++t) {
            const h8 a1 = *reinterpret_cast<const h8*>(aB1 + (t * 16 + ks) * 512);
            const h8 a2 = *reinterpret_cast<const h8*>(aB2 + (t * 16 + ks) * 512);
            #pragma unroll
            for (int ni = 0; ni < 4; ++ni) {
                accA[t][ni] = __builtin_amdgcn_mfma_f32_16x16x32_f16(a1, wf1[ni], accA[t][ni], 0, 0, 0);
                accB[t][ni] = __builtin_amdgcn_mfma_f32_16x16x32_f16(a1, wf2[ni], accB[t][ni], 0, 0, 0);
                accB[t][ni] = __builtin_amdgcn_mfma_f32_16x16x32_f16(a2, wf1[ni], accB[t][ni], 0, 0, 0);
            }
        }
    }

    // ---- in-register BN + LIF epilogue (wave owns all 4 t of its rows) ----
    #pragma unroll
    for (int ni = 0; ni < 4; ++ni) {
        const int c = col0 + ni * 16 + lr;
        const float sc = gam[c] * (1.0f / sqrtf(rva[c] + EPSf));
        const float bi = bias[c], mn = mea[c], be = bet[c];
        #pragma unroll
        for (int r = 0; r < 4; ++r) {
            const int bn = row0 + wv * 16 + lk * 4 + r;  // C/D: row=(l>>4)*4+reg, col=l&15
            float vm = 0.0f;
            #pragma unroll
            for (int t = 0; t < 4; ++t) {
                const float res = accA[t][ni][r] + INV4096 * accB[t][ni][r];
                const float y = ((res + bi) - mn) * sc + be;
                vm = vm + (y - vm) * 0.5f;
                const float s = (vm >= 1.0f) ? 1.0f : 0.0f;
                vm = (s != 0.0f) ? 0.0f : vm;
                const int b = bn >> 9, n = bn & 511;
                out[((((size_t)t * B_ + b) * H_ + ct) * N_ + n) * D_ + ni * 16 + lr] =
                    __float2bfloat16(s);
            }
        }
    }
}

// ---- p-GEMM (A = exact f16 spikes, packed), W split, out fp32 ----
__global__ __launch_bounds__(256, 2)
void mfma_gemm_p(const _Float16* __restrict__ A1p,
                 const _Float16* __restrict__ Wp1, const _Float16* __restrict__ Wp2,
                 const float* __restrict__ bias, const float* __restrict__ gam,
                 const float* __restrict__ bet, const float* __restrict__ mea,
                 const float* __restrict__ rva, float* __restrict__ out_plain)
{
    const int id = blockIdx.x;
    const int bt = (id & 7) * 8 + ((id >> 3) & 7);
    const int ct = id >> 6;
    const int wv = threadIdx.x >> 6, lane = threadIdx.x & 63;
    const int rt = bt * 4 + wv;
    const int row0 = bt * 64, col0 = ct * 64;
    const int lr = lane & 15, lk = lane >> 4;

    f4 accA[4][4], accB[4][4];
    #pragma unroll
    for (int t = 0; t < 4; ++t)
        #pragma unroll
        for (int ni = 0; ni < 4; ++ni) { accA[t][ni] = (f4)0.0f; accB[t][ni] = (f4)0.0f; }

    const _Float16* aB1 = A1p + (size_t)rt * 32768 + lane * 8;
    const _Float16* wB1 = Wp1 + (size_t)ct * 32768 + lane * 8;
    const _Float16* wB2 = Wp2 + (size_t)ct * 32768 + lane * 8;

    #pragma unroll
    for (int ks = 0; ks < 16; ++ks) {
        h8 wf1[4], wf2[4];
        #pragma unroll
        for (int ni = 0; ni < 4; ++ni) {
            wf1[ni] = *reinterpret_cast<const h8*>(wB1 + (ks * 4 + ni) * 512);
            wf2[ni] = *reinterpret_cast<const h8*>(wB2 + (ks * 4 + ni) * 512);
        }
        #pragma unroll
        for (int t = 0; t < 4; ++t) {
            const h8 a1 = *reinterpret_cast<const h8*>(aB1 + (t * 16 + ks) * 512);
            #pragma unroll
            for (int ni = 0; ni < 4; ++ni) {
                accA[t][ni] = __builtin_amdgcn_mfma_f32_16x16x32_f16(a1, wf1[ni], accA[t][ni], 0, 0, 0);
                accB[t][ni] = __builtin_amdgcn_mfma_f32_16x16x32_f16(a1, wf2[ni], accB[t][ni], 0, 0, 0);
            }
        }
    }

    #pragma unroll
    for (int ni = 0; ni < 4; ++ni) {
        const int c = col0 + ni * 16 + lr;
        const float sc = gam[c] * (1.0f / sqrtf(rva[c] + EPSf));
        const float bi = bias[c], mn = mea[c], be = bet[c];
        #pragma unroll
        for (int r = 0; r < 4; ++r) {
            const int bn = row0 + wv * 16 + lk * 4 + r;
            float vm = 0.0f;
            #pragma unroll
            for (int t = 0; t < 4; ++t) {
                const float res = accA[t][ni][r] + INV4096 * accB[t][ni][r];
                const float y = ((res + bi) - mn) * sc + be;
                vm = vm + (y - vm) * 0.5f;
                const float s = (vm >= 1.0f) ? 1.0f : 0.0f;
                vm = (s != 0.0f) ? 0.0f : vm;
                out_plain[((size_t)t * BNR + bn) * C_ + c] = s;
            }
        }
    }
}

// ---- kv[d1][d2] = sum_n k[n,d1]*v[n,d2] per (t,b,h) ----
__global__ __launch_bounds__(256)
void ktv_kernel(const __hip_bfloat16* __restrict__ sk, const __hip_bfloat16* __restrict__ sv,
                float* __restrict__ kv)
{
    __shared__ __hip_bfloat16 kl[64][64];
    __shared__ __hip_bfloat16 vl[64][64];
    const int tbh = blockIdx.x;
    const int tid = threadIdx.x;
    const int tx = tid & 15, ty = tid >> 4;
    const size_t base = (size_t)tbh * N_ * D_;
    float acc[4][4] = {};
    for (int n0 = 0; n0 < N_; n0 += 64) {
        __syncthreads();
        #pragma unroll
        for (int p = 0; p < 2; ++p) {
            const int idx = tid + p * 256;
            const int r = idx >> 3, c8 = (idx & 7) * 8;
            *reinterpret_cast<float4*>(&kl[r][c8]) =
                *reinterpret_cast<const float4*>(&sk[base + (size_t)(n0 + r) * D_ + c8]);
            *reinterpret_cast<float4*>(&vl[r][c8]) =
                *reinterpret_cast<const float4*>(&sv[base + (size_t)(n0 + r) * D_ + c8]);
        }
        __syncthreads();
        for (int nn = 0; nn < 64; ++nn) {
            float a[4], b[4];
            #pragma unroll
            for (int i = 0; i < 4; ++i) a[i] = __bfloat162float(kl[nn][ty * 4 + i]);
            #pragma unroll
            for (int j = 0; j < 4; ++j) b[j] = __bfloat162float(vl[nn][tx * 4 + j]);
            #pragma unroll
            for (int i = 0; i < 4; ++i)
                #pragma unroll
                for (int j = 0; j < 4; ++j)
                    acc[i][j] = fmaf(a[i], b[j], acc[i][j]);
        }
    }
    float* out = kv + (size_t)tbh * 4096;
    #pragma unroll
    for (int i = 0; i < 4; ++i)
        #pragma unroll
        for (int j = 0; j < 4; ++j)
            out[(ty * 4 + i) * 64 + tx * 4 + j] = acc[i][j];
}

// ---- o = 0.125 * q @ kv, fused attn-LIF (vth=0.5); writes packed f16 spikes ----
__global__ __launch_bounds__(256)
void qkv_lif_kernel(const __hip_bfloat16* __restrict__ sq, const float* __restrict__ kv,
                    _Float16* __restrict__ osp)
{
    __shared__ float kvl[64][64];
    __shared__ __hip_bfloat16 ql[64][64];
    const int nt = blockIdx.x, b = blockIdx.y, h = blockIdx.z;
    const int tid = threadIdx.x;
    const int tx = tid & 15, ty = tid >> 4;
    const int n0 = nt * 64;
    float v[4][4] = {};
    for (int t = 0; t < T_; ++t) {
        const int tbh = (t * B_ + b) * H_ + h;
        __syncthreads();
        #pragma unroll
        for (int p = 0; p < 16; ++p) {
            const int idx = p * 256 + tid;
            kvl[idx >> 6][idx & 63] = kv[(size_t)tbh * 4096 + idx];
        }
        #pragma unroll
        for (int p = 0; p < 2; ++p) {
            const int idx = tid + p * 256;
            const int r = idx >> 3, c8 = (idx & 7) * 8;
            *reinterpret_cast<float4*>(&ql[r][c8]) =
                *reinterpret_cast<const float4*>(&sq[((size_t)tbh * N_ + n0 + r) * D_ + c8]);
        }
        __syncthreads();
        float acc[4][4] = {};
        for (int dd = 0; dd < 64; ++dd) {
            float a[4], bb[4];
            #pragma unroll
            for (int i = 0; i < 4; ++i) a[i] = __bfloat162float(ql[ty * 4 + i][dd]);
            #pragma unroll
            for (int j = 0; j < 4; ++j) bb[j] = kvl[dd][tx * 4 + j];
            #pragma unroll
            for (int i = 0; i < 4; ++i)
                #pragma unroll
                for (int j = 0; j < 4; ++j)
                    acc[i][j] = fmaf(a[i], bb[j], acc[i][j]);
        }
        #pragma unroll
        for (int i = 0; i < 4; ++i) {
            const int row_bn = b * N_ + n0 + ty * 4 + i;
            const int c0 = h * 64 + tx * 4;
            const int rt = row_bn >> 4, rlo = row_bn & 15;
            const int ks = c0 >> 5, lk3 = (c0 >> 3) & 3, j0 = c0 & 7;
            h4v sp;
            #pragma unroll
            for (int j = 0; j < 4; ++j) {
                const float y = 0.125f * acc[i][j];     // exact (integer counts)
                float vv = v[i][j];
                vv = vv + (y - vv) * 0.5f;
                const float s = (vv >= 0.5f) ? 1.0f : 0.0f;
                sp[j] = (_Float16)s;
                v[i][j] = (s != 0.0f) ? 0.0f : vv;
            }
            _Float16* dst = osp + ((((size_t)rt * 4 + t) * 16 + ks) * 64 + lk3 * 16 + rlo) * 8 + j0;
            *reinterpret_cast<h4v*>(dst) = sp;
        }
    }
}

extern "C" void kernel_launch(void* const* d_in, const int* in_sizes, int n_in,
                              void* d_out, int out_size, void* d_ws, size_t ws_size,
                              hipStream_t stream)
{
    const float* x = (const float*)d_in[0];
    const float *W[4], *bia[4], *gam[4], *bet[4], *mea[4], *rva[4];
    for (int br = 0; br < 4; ++br) {
        W[br]   = (const float*)d_in[1 + 6 * br + 0];
        bia[br] = (const float*)d_in[1 + 6 * br + 1];
        gam[br] = (const float*)d_in[1 + 6 * br + 2];
        bet[br] = (const float*)d_in[1 + 6 * br + 3];
        mea[br] = (const float*)d_in[1 + 6 * br + 4];
        rva[br] = (const float*)d_in[1 + 6 * br + 5];
    }
    char* ws = (char*)d_ws;
    _Float16* x1 = (_Float16*)(ws + 0);
    _Float16* x2 = (_Float16*)(ws + 16777216);
    __hip_bfloat16* sq = (__hip_bfloat16*)(ws + 33554432);
    __hip_bfloat16* sk = (__hip_bfloat16*)(ws + 50331648);
    __hip_bfloat16* sv = (__hip_bfloat16*)(ws + 67108864);
    _Float16* w1[4], *w2[4];
    for (int br = 0; br < 4; ++br) {
        w1[br] = (_Float16*)(ws + 83886080 + (size_t)br * 1048576);
        w2[br] = (_Float16*)(ws + 83886080 + (size_t)br * 1048576 + 524288);
    }
    float*    kv  = (float*)(ws + 16777216);     // aliases x2 (dead after gemm3)
    _Float16* osp = (_Float16*)(ws + 0);         // aliases x1 (dead after gemm3)

    dim3 blk(256);
    split_pack_x<<<dim3(4096), blk, 0, stream>>>(x, x1, x2);
    pack_w_all<<<dim3(512), blk, 0, stream>>>(W[0], W[1], W[2], W[3],
        w1[0], w2[0], w1[1], w2[1], w1[2], w2[2], w1[3], w2[3]);

    gemm3_bn_lif<<<dim3(512, 3), blk, 0, stream>>>(x1, x2,
        w1[0], w2[0], w1[1], w2[1], w1[2], w2[2],
        bia[0], gam[0], bet[0], mea[0], rva[0],
        bia[1], gam[1], bet[1], mea[1], rva[1],
        bia[2], gam[2], bet[2], mea[2], rva[2],
        sq, sk, sv);

    ktv_kernel<<<dim3(T_ * B_ * H_), blk, 0, stream>>>(sk, sv, kv);
    qkv_lif_kernel<<<dim3(N_ / 64, B_, H_), blk, 0, stream>>>(sq, kv, osp);

    mfma_gemm_p<<<dim3(512), blk, 0, stream>>>(osp, w1[3], w2[3],
        bia[3], gam[3], bet[3], mea[3], rva[3], (float*)d_out);
}

// Round 9
// 179.494 us; speedup vs baseline: 3.1656x; 1.0473x over previous
//
#include <hip/hip_runtime.h>
#include <hip/hip_bf16.h>

typedef _Float16 h8 __attribute__((ext_vector_type(8)));
typedef _Float16 h4v __attribute__((ext_vector_type(4)));
typedef float f4 __attribute__((ext_vector_type(4)));

#define T_ 4
#define B_ 8
#define N_ 512
#define C_ 512
#define H_ 8
#define D_ 64
#define BNR 4096
#define EPSf 1e-5f
#define F16_MIN_NORM 6.1035156e-05f
#define INV4096 0.000244140625f

// ---- x -> (h1 + 2^-12 * h2) f16 split, packed MFMA-fragment-linear ----
// A1p/A2p[rt][t][ks][lane][8]: lane l holds x[t][rt*16 + (l&15)][ks*32 + (l>>4)*8 ..+8]
__global__ __launch_bounds__(256)
void split_pack_x(const float* __restrict__ in, _Float16* __restrict__ h1,
                  _Float16* __restrict__ h2)
{
    const int gid = blockIdx.x * 256 + threadIdx.x;    // 1048576 h8-groups
    const int lane = gid & 63;
    const int ks = (gid >> 6) & 15;
    const int t = (gid >> 10) & 3;
    const int rt = gid >> 12;
    const int row = rt * 16 + (lane & 15);
    const size_t src = ((size_t)t * BNR + row) * C_ + ks * 32 + (lane >> 4) * 8;
    const float4 x0 = *reinterpret_cast<const float4*>(in + src);
    const float4 x1 = *reinterpret_cast<const float4*>(in + src + 4);
    h8 a, b;
    #pragma unroll
    for (int j = 0; j < 8; ++j) {
        const float xv = (j < 4) ? (&x0.x)[j] : (&x1.x)[j - 4];
        const float hi = (fabsf(xv) >= F16_MIN_NORM) ? xv : 0.0f;  // no subnormal x1
        const _Float16 h = (_Float16)hi;
        const float r = (xv - (float)h) * 4096.0f;                 // normal-range residual
        a[j] = h; b[j] = (_Float16)r;
    }
    *reinterpret_cast<h8*>(h1 + (size_t)gid * 8) = a;
    *reinterpret_cast<h8*>(h2 + (size_t)gid * 8) = b;
}

// ---- W -> split + MFMA-fragment-linear pack, all 4 branches in one launch ----
__device__ __forceinline__
void pack_w_one(const float* __restrict__ W, _Float16* __restrict__ Wp1,
                _Float16* __restrict__ Wp2, int gid)
{
    const int lane = gid & 63;
    const int ni = (gid >> 6) & 3;
    const int ks = (gid >> 8) & 15;
    const int ct = gid >> 12;
    const int col = ct * 64 + ni * 16 + (lane & 15);
    const int k = ks * 32 + (lane >> 4) * 8;
    const float* src = W + (size_t)col * C_ + k;
    h8 a, b;
    #pragma unroll
    for (int j = 0; j < 8; ++j) {
        const float xv = src[j];
        const float hi = (fabsf(xv) >= F16_MIN_NORM) ? xv : 0.0f;
        const _Float16 h = (_Float16)hi;
        const float r = (xv - (float)h) * 4096.0f;
        a[j] = h; b[j] = (_Float16)r;
    }
    *reinterpret_cast<h8*>(Wp1 + (size_t)gid * 8) = a;
    *reinterpret_cast<h8*>(Wp2 + (size_t)gid * 8) = b;
}

__global__ __launch_bounds__(256)
void pack_w_all(const float* __restrict__ Wq, const float* __restrict__ Wk,
                const float* __restrict__ Wv, const float* __restrict__ Wp,
                _Float16* q1, _Float16* q2, _Float16* k1, _Float16* k2,
                _Float16* v1, _Float16* v2, _Float16* p1, _Float16* p2)
{
    const int g = blockIdx.x * 256 + threadIdx.x;     // 131072
    const int br = g >> 15;                            // uniform per block
    const int gid = g & 32767;
    if (br == 0)      pack_w_one(Wq, q1, q2, gid);
    else if (br == 1) pack_w_one(Wk, k1, k2, gid);
    else if (br == 2) pack_w_one(Wv, v1, v2, gid);
    else              pack_w_one(Wp, p1, p2, gid);
}

// ---- gemm3: 512 threads, 8 waves = (tp in {0,1}) x (wr in 0..3) ----
// Wave (tp,wr): rows [bt*64+16*wr,+16) x 64 cols x t in {2tp,2tp+1}.
// W staged to LDS dbuf once/block/k-step via global_load_lds (8KB), A read
// direct fragment-packed (4KB/wave/step). acc=64 regs -> 2 blocks/CU, 16 waves.
// LIF t-recurrence crosses the tp split: tp=0 passes exact v-state after t1
// through LDS (reusing the W buffers), tp=1 continues t2,t3 -> bit-identical.
__global__ __launch_bounds__(512, 4)
void gemm3_bn_lif(const _Float16* __restrict__ A1p, const _Float16* __restrict__ A2p,
                  const _Float16* __restrict__ Wq1, const _Float16* __restrict__ Wq2,
                  const _Float16* __restrict__ Wk1, const _Float16* __restrict__ Wk2,
                  const _Float16* __restrict__ Wv1, const _Float16* __restrict__ Wv2,
                  const float* __restrict__ biq, const float* __restrict__ gaq,
                  const float* __restrict__ beq, const float* __restrict__ meq,
                  const float* __restrict__ rvq,
                  const float* __restrict__ bik, const float* __restrict__ gak,
                  const float* __restrict__ bek, const float* __restrict__ mek,
                  const float* __restrict__ rvk,
                  const float* __restrict__ biv, const float* __restrict__ gav,
                  const float* __restrict__ bev, const float* __restrict__ mev,
                  const float* __restrict__ rvv,
                  __hip_bfloat16* __restrict__ oq, __hip_bfloat16* __restrict__ ok,
                  __hip_bfloat16* __restrict__ ov)
{
    __shared__ __align__(16) char wsm[16384];           // 2 x 8KB W dbuf; reused as v-state
    const int br = blockIdx.y;                          // uniform
    const _Float16* W1 = (br == 0) ? Wq1 : (br == 1) ? Wk1 : Wv1;
    const _Float16* W2 = (br == 0) ? Wq2 : (br == 1) ? Wk2 : Wv2;
    const float* bias = (br == 0) ? biq : (br == 1) ? bik : biv;
    const float* gam  = (br == 0) ? gaq : (br == 1) ? gak : gav;
    const float* bet  = (br == 0) ? beq : (br == 1) ? bek : bev;
    const float* mea  = (br == 0) ? meq : (br == 1) ? mek : mev;
    const float* rva  = (br == 0) ? rvq : (br == 1) ? rvk : rvv;
    __hip_bfloat16* out = (br == 0) ? oq : (br == 1) ? ok : ov;

    const int id = blockIdx.x;
    const int bt = (id & 7) * 8 + ((id >> 3) & 7);      // XCD-aware swizzle
    const int ct = id >> 6;
    const int tid = threadIdx.x;
    const int wave = tid >> 6, lane = tid & 63;
    const int tp = wave & 1, wr = wave >> 1;
    const int rt = bt * 4 + wr;
    const int row0 = bt * 64, col0 = ct * 64;
    const int lr = lane & 15, lk = lane >> 4;

    f4 accA[2][4], accB[2][4];                          // [ti][ni], t = 2*tp + ti
    #pragma unroll
    for (int ti = 0; ti < 2; ++ti)
        #pragma unroll
        for (int ni = 0; ni < 4; ++ni) { accA[ti][ni] = (f4)0.0f; accB[ti][ni] = (f4)0.0f; }

    const _Float16* aB1 = A1p + (size_t)rt * 32768 + lane * 8;
    const _Float16* aB2 = A2p + (size_t)rt * 32768 + lane * 8;
    // per-wave W staging slot: split s_=wave>>2, frag q_=wave&3 (wave-uniform)
    const int s_ = wave >> 2, q_ = wave & 3;
    const _Float16* wsrc = (s_ ? W2 : W1) + (size_t)ct * 32768 + q_ * 512 + lane * 8;
    const int wdoff = s_ * 4096 + q_ * 1024;

    auto stageW = [&](int ks, int b) {
        __builtin_amdgcn_global_load_lds(
            (const __attribute__((address_space(1))) unsigned int*)(wsrc + ks * 2048),
            (__attribute__((address_space(3))) unsigned int*)(wsm + b * 8192 + wdoff),
            16, 0, 0);
    };

    stageW(0, 0);
    #pragma unroll 2
    for (int ks = 0; ks < 16; ++ks) {
        const int buf = ks & 1;
        __syncthreads();                                // W[buf] ready; buf^1 reads done
        if (ks < 15) stageW(ks + 1, buf ^ 1);
        h8 a1[2], a2[2];
        #pragma unroll
        for (int ti = 0; ti < 2; ++ti) {
            const int t = tp * 2 + ti;
            a1[ti] = *reinterpret_cast<const h8*>(aB1 + (t * 16 + ks) * 512);
            a2[ti] = *reinterpret_cast<const h8*>(aB2 + (t * 16 + ks) * 512);
        }
        const char* wb = wsm + buf * 8192;
        #pragma unroll
        for (int ni = 0; ni < 4; ++ni) {
            const h8 wf1 = *reinterpret_cast<const h8*>(wb + ni * 1024 + lane * 16);
            const h8 wf2 = *reinterpret_cast<const h8*>(wb + 4096 + ni * 1024 + lane * 16);
            #pragma unroll
            for (int ti = 0; ti < 2; ++ti) {
                accA[ti][ni] = __builtin_amdgcn_mfma_f32_16x16x32_f16(a1[ti], wf1, accA[ti][ni], 0, 0, 0);
                accB[ti][ni] = __builtin_amdgcn_mfma_f32_16x16x32_f16(a1[ti], wf2, accB[ti][ni], 0, 0, 0);
                accB[ti][ni] = __builtin_amdgcn_mfma_f32_16x16x32_f16(a2[ti], wf1, accB[ti][ni], 0, 0, 0);
            }
        }
    }

    // ---- BN + LIF epilogue with t-split handoff via LDS ----
    float* vst = (float*)wsm;                           // [64 rows][64 cols] fp32
    float sc[4], bi[4], mn[4], be[4];
    #pragma unroll
    for (int ni = 0; ni < 4; ++ni) {
        const int c = col0 + ni * 16 + lr;
        sc[ni] = gam[c] * (1.0f / sqrtf(rva[c] + EPSf));
        bi[ni] = bias[c]; mn[ni] = mea[c]; be[ni] = bet[c];
    }
    __syncthreads();                                    // all W-buffer reads done
    if (tp == 0) {
        #pragma unroll
        for (int ni = 0; ni < 4; ++ni)
            #pragma unroll
            for (int r = 0; r < 4; ++r) {
                const int rl = wr * 16 + lk * 4 + r;    // local row 0..63
                const int bn = row0 + rl;
                float vm = 0.0f;
                #pragma unroll
                for (int ti = 0; ti < 2; ++ti) {        // t = 0,1
                    const float res = accA[ti][ni][r] + INV4096 * accB[ti][ni][r];
                    const float y = ((res + bi[ni]) - mn[ni]) * sc[ni] + be[ni];
                    vm = vm + (y - vm) * 0.5f;
                    const float s = (vm >= 1.0f) ? 1.0f : 0.0f;
                    vm = (s != 0.0f) ? 0.0f : vm;
                    const int b = bn >> 9, n = bn & 511;
                    out[((((size_t)ti * B_ + b) * H_ + ct) * N_ + n) * D_ + ni * 16 + lr] =
                        __float2bfloat16(s);
                }
                vst[rl * 64 + ni * 16 + lr] = vm;       // exact v after t=1
            }
    }
    __syncthreads();
    if (tp == 1) {
        #pragma unroll
        for (int ni = 0; ni < 4; ++ni)
            #pragma unroll
            for (int r = 0; r < 4; ++r) {
                const int rl = wr * 16 + lk * 4 + r;
                const int bn = row0 + rl;
                float vm = vst[rl * 64 + ni * 16 + lr];
                #pragma unroll
                for (int ti = 0; ti < 2; ++ti) {        // t = 2,3
                    const float res = accA[ti][ni][r] + INV4096 * accB[ti][ni][r];
                    const float y = ((res + bi[ni]) - mn[ni]) * sc[ni] + be[ni];
                    vm = vm + (y - vm) * 0.5f;
                    const float s = (vm >= 1.0f) ? 1.0f : 0.0f;
                    vm = (s != 0.0f) ? 0.0f : vm;
                    const int b = bn >> 9, n = bn & 511;
                    out[((((size_t)(2 + ti) * B_ + b) * H_ + ct) * N_ + n) * D_ + ni * 16 + lr] =
                        __float2bfloat16(s);
                }
            }
    }
}

// ---- p-GEMM (A = exact f16 spikes, packed), W split, out fp32 ----
__global__ __launch_bounds__(256, 2)
void mfma_gemm_p(const _Float16* __restrict__ A1p,
                 const _Float16* __restrict__ Wp1, const _Float16* __restrict__ Wp2,
                 const float* __restrict__ bias, const float* __restrict__ gam,
                 const float* __restrict__ bet, const float* __restrict__ mea,
                 const float* __restrict__ rva, float* __restrict__ out_plain)
{
    const int id = blockIdx.x;
    const int bt = (id & 7) * 8 + ((id >> 3) & 7);
    const int ct = id >> 6;
    const int wv = threadIdx.x >> 6, lane = threadIdx.x & 63;
    const int rt = bt * 4 + wv;
    const int row0 = bt * 64, col0 = ct * 64;
    const int lr = lane & 15, lk = lane >> 4;

    f4 accA[4][4], accB[4][4];
    #pragma unroll
    for (int t = 0; t < 4; ++t)
        #pragma unroll
        for (int ni = 0; ni < 4; ++ni) { accA[t][ni] = (f4)0.0f; accB[t][ni] = (f4)0.0f; }

    const _Float16* aB1 = A1p + (size_t)rt * 32768 + lane * 8;
    const _Float16* wB1 = Wp1 + (size_t)ct * 32768 + lane * 8;
    const _Float16* wB2 = Wp2 + (size_t)ct * 32768 + lane * 8;

    #pragma unroll
    for (int ks = 0; ks < 16; ++ks) {
        h8 wf1[4], wf2[4];
        #pragma unroll
        for (int ni = 0; ni < 4; ++ni) {
            wf1[ni] = *reinterpret_cast<const h8*>(wB1 + (ks * 4 + ni) * 512);
            wf2[ni] = *reinterpret_cast<const h8*>(wB2 + (ks * 4 + ni) * 512);
        }
        #pragma unroll
        for (int t = 0; t < 4; ++t) {
            const h8 a1 = *reinterpret_cast<const h8*>(aB1 + (t * 16 + ks) * 512);
            #pragma unroll
            for (int ni = 0; ni < 4; ++ni) {
                accA[t][ni] = __builtin_amdgcn_mfma_f32_16x16x32_f16(a1, wf1[ni], accA[t][ni], 0, 0, 0);
                accB[t][ni] = __builtin_amdgcn_mfma_f32_16x16x32_f16(a1, wf2[ni], accB[t][ni], 0, 0, 0);
            }
        }
    }

    #pragma unroll
    for (int ni = 0; ni < 4; ++ni) {
        const int c = col0 + ni * 16 + lr;
        const float sc = gam[c] * (1.0f / sqrtf(rva[c] + EPSf));
        const float bi = bias[c], mn = mea[c], be = bet[c];
        #pragma unroll
        for (int r = 0; r < 4; ++r) {
            const int bn = row0 + wv * 16 + lk * 4 + r;
            float vm = 0.0f;
            #pragma unroll
            for (int t = 0; t < 4; ++t) {
                const float res = accA[t][ni][r] + INV4096 * accB[t][ni][r];
                const float y = ((res + bi) - mn) * sc + be;
                vm = vm + (y - vm) * 0.5f;
                const float s = (vm >= 1.0f) ? 1.0f : 0.0f;
                vm = (s != 0.0f) ? 0.0f : vm;
                out_plain[((size_t)t * BNR + bn) * C_ + c] = s;
            }
        }
    }
}

// ---- kv[d1][d2] = sum_n k[n,d1]*v[n,d2] per (t,b,h) ----
__global__ __launch_bounds__(256)
void ktv_kernel(const __hip_bfloat16* __restrict__ sk, const __hip_bfloat16* __restrict__ sv,
                float* __restrict__ kv)
{
    __shared__ __hip_bfloat16 kl[64][64];
    __shared__ __hip_bfloat16 vl[64][64];
    const int tbh = blockIdx.x;
    const int tid = threadIdx.x;
    const int tx = tid & 15, ty = tid >> 4;
    const size_t base = (size_t)tbh * N_ * D_;
    float acc[4][4] = {};
    for (int n0 = 0; n0 < N_; n0 += 64) {
        __syncthreads();
        #pragma unroll
        for (int p = 0; p < 2; ++p) {
            const int idx = tid + p * 256;
            const int r = idx >> 3, c8 = (idx & 7) * 8;
            *reinterpret_cast<float4*>(&kl[r][c8]) =
                *reinterpret_cast<const float4*>(&sk[base + (size_t)(n0 + r) * D_ + c8]);
            *reinterpret_cast<float4*>(&vl[r][c8]) =
                *reinterpret_cast<const float4*>(&sv[base + (size_t)(n0 + r) * D_ + c8]);
        }
        __syncthreads();
        for (int nn = 0; nn < 64; ++nn) {
            float a[4], b[4];
            #pragma unroll
            for (int i = 0; i < 4; ++i) a[i] = __bfloat162float(kl[nn][ty * 4 + i]);
            #pragma unroll
            for (int j = 0; j < 4; ++j) b[j] = __bfloat162float(vl[nn][tx * 4 + j]);
            #pragma unroll
            for (int i = 0; i < 4; ++i)
                #pragma unroll
                for (int j = 0; j < 4; ++j)
                    acc[i][j] = fmaf(a[i], b[j], acc[i][j]);
        }
    }
    float* out = kv + (size_t)tbh * 4096;
    #pragma unroll
    for (int i = 0; i < 4; ++i)
        #pragma unroll
        for (int j = 0; j < 4; ++j)
            out[(ty * 4 + i) * 64 + tx * 4 + j] = acc[i][j];
}

// ---- o = 0.125 * q @ kv, fused attn-LIF (vth=0.5); writes packed f16 spikes ----
__global__ __launch_bounds__(256)
void qkv_lif_kernel(const __hip_bfloat16* __restrict__ sq, const float* __restrict__ kv,
                    _Float16* __restrict__ osp)
{
    __shared__ float kvl[64][64];
    __shared__ __hip_bfloat16 ql[64][64];
    const int nt = blockIdx.x, b = blockIdx.y, h = blockIdx.z;
    const int tid = threadIdx.x;
    const int tx = tid & 15, ty = tid >> 4;
    const int n0 = nt * 64;
    float v[4][4] = {};
    for (int t = 0; t < T_; ++t) {
        const int tbh = (t * B_ + b) * H_ + h;
        __syncthreads();
        #pragma unroll
        for (int p = 0; p < 16; ++p) {
            const int idx = p * 256 + tid;
            kvl[idx >> 6][idx & 63] = kv[(size_t)tbh * 4096 + idx];
        }
        #pragma unroll
        for (int p = 0; p < 2; ++p) {
            const int idx = tid + p * 256;
            const int r = idx >> 3, c8 = (idx & 7) * 8;
            *reinterpret_cast<float4*>(&ql[r][c8]) =
                *reinterpret_cast<const float4*>(&sq[((size_t)tbh * N_ + n0 + r) * D_ + c8]);
        }
        __syncthreads();
        float acc[4][4] = {};
        for (int dd = 0; dd < 64; ++dd) {
            float a[4], bb[4];
            #pragma unroll
            for (int i = 0; i < 4; ++i) a[i] = __bfloat162float(ql[ty * 4 + i][dd]);
            #pragma unroll
            for (int j = 0; j < 4; ++j) bb[j] = kvl[dd][tx * 4 + j];
            #pragma unroll
            for (int i = 0; i < 4; ++i)
                #pragma unroll
                for (int j = 0; j < 4; ++j)
                    acc[i][j] = fmaf(a[i], bb[j], acc[i][j]);
        }
        #pragma unroll
        for (int i = 0; i < 4; ++i) {
            const int row_bn = b * N_ + n0 + ty * 4 + i;
            const int c0 = h * 64 + tx * 4;
            const int rt = row_bn >> 4, rlo = row_bn & 15;
            const int ks = c0 >> 5, lk3 = (c0 >> 3) & 3, j0 = c0 & 7;
            h4v sp;
            #pragma unroll
            for (int j = 0; j < 4; ++j) {
                const float y = 0.125f * acc[i][j];     // exact (integer counts)
                float vv = v[i][j];
                vv = vv + (y - vv) * 0.5f;
                const float s = (vv >= 0.5f) ? 1.0f : 0.0f;
                sp[j] = (_Float16)s;
                v[i][j] = (s != 0.0f) ? 0.0f : vv;
            }
            _Float16* dst = osp + ((((size_t)rt * 4 + t) * 16 + ks) * 64 + lk3 * 16 + rlo) * 8 + j0;
            *reinterpret_cast<h4v*>(dst) = sp;
        }
    }
}

extern "C" void kernel_launch(void* const* d_in, const int* in_sizes, int n_in,
                              void* d_out, int out_size, void* d_ws, size_t ws_size,
                              hipStream_t stream)
{
    const float* x = (const float*)d_in[0];
    const float *W[4], *bia[4], *gam[4], *bet[4], *mea[4], *rva[4];
    for (int br = 0; br < 4; ++br) {
        W[br]   = (const float*)d_in[1 + 6 * br + 0];
        bia[br] = (const float*)d_in[1 + 6 * br + 1];
        gam[br] = (const float*)d_in[1 + 6 * br + 2];
        bet[br] = (const float*)d_in[1 + 6 * br + 3];
        mea[br] = (const float*)d_in[1 + 6 * br + 4];
        rva[br] = (const float*)d_in[1 + 6 * br + 5];
    }
    char* ws = (char*)d_ws;
    _Float16* x1 = (_Float16*)(ws + 0);
    _Float16* x2 = (_Float16*)(ws + 16777216);
    __hip_bfloat16* sq = (__hip_bfloat16*)(ws + 33554432);
    __hip_bfloat16* sk = (__hip_bfloat16*)(ws + 50331648);
    __hip_bfloat16* sv = (__hip_bfloat16*)(ws + 67108864);
    _Float16* w1[4], *w2[4];
    for (int br = 0; br < 4; ++br) {
        w1[br] = (_Float16*)(ws + 83886080 + (size_t)br * 1048576);
        w2[br] = (_Float16*)(ws + 83886080 + (size_t)br * 1048576 + 524288);
    }
    float*    kv  = (float*)(ws + 16777216);     // aliases x2 (dead after gemm3)
    _Float16* osp = (_Float16*)(ws + 0);         // aliases x1 (dead after gemm3)

    dim3 blk(256);
    split_pack_x<<<dim3(4096), blk, 0, stream>>>(x, x1, x2);
    pack_w_all<<<dim3(512), blk, 0, stream>>>(W[0], W[1], W[2], W[3],
        w1[0], w2[0], w1[1], w2[1], w1[2], w2[2], w1[3], w2[3]);

    gemm3_bn_lif<<<dim3(512, 3), dim3(512), 0, stream>>>(x1, x2,
        w1[0], w2[0], w1[1], w2[1], w1[2], w2[2],
        bia[0], gam[0], bet[0], mea[0], rva[0],
        bia[1], gam[1], bet[1], mea[1], rva[1],
        bia[2], gam[2], bet[2], mea[2], rva[2],
        sq, sk, sv);

    ktv_kernel<<<dim3(T_ * B_ * H_), blk, 0, stream>>>(sk, sv, kv);
    qkv_lif_kernel<<<dim3(N_ / 64, B_, H_), blk, 0, stream>>>(sq, kv, osp);

    mfma_gemm_p<<<dim3(512), blk, 0, stream>>>(osp, w1[3], w2[3],
        bia[3], gam[3], bet[3], mea[3], rva[3], (float*)d_out);
}

// Round 10
// 174.812 us; speedup vs baseline: 3.2504x; 1.0268x over previous
//
#include <hip/hip_runtime.h>
#include <hip/hip_bf16.h>

typedef _Float16 h8 __attribute__((ext_vector_type(8)));
typedef _Float16 h4v __attribute__((ext_vector_type(4)));
typedef float f4 __attribute__((ext_vector_type(4)));

#define T_ 4
#define B_ 8
#define N_ 512
#define C_ 512
#define H_ 8
#define D_ 64
#define BNR 4096
#define EPSf 1e-5f
#define F16_MIN_NORM 6.1035156e-05f
#define INV4096 0.000244140625f

// ---- x -> (h1 + 2^-12 * h2) f16 split, packed MFMA-fragment-linear ----
// A1p/A2p[rt][t][ks][lane][8]: lane l holds x[t][rt*16 + (l&15)][ks*32 + (l>>4)*8 ..+8]
__global__ __launch_bounds__(256)
void split_pack_x(const float* __restrict__ in, _Float16* __restrict__ h1,
                  _Float16* __restrict__ h2)
{
    const int gid = blockIdx.x * 256 + threadIdx.x;    // 1048576 h8-groups
    const int lane = gid & 63;
    const int ks = (gid >> 6) & 15;
    const int t = (gid >> 10) & 3;
    const int rt = gid >> 12;
    const int row = rt * 16 + (lane & 15);
    const size_t src = ((size_t)t * BNR + row) * C_ + ks * 32 + (lane >> 4) * 8;
    const float4 x0 = *reinterpret_cast<const float4*>(in + src);
    const float4 x1 = *reinterpret_cast<const float4*>(in + src + 4);
    h8 a, b;
    #pragma unroll
    for (int j = 0; j < 8; ++j) {
        const float xv = (j < 4) ? (&x0.x)[j] : (&x1.x)[j - 4];
        const float hi = (fabsf(xv) >= F16_MIN_NORM) ? xv : 0.0f;  // no subnormal x1
        const _Float16 h = (_Float16)hi;
        const float r = (xv - (float)h) * 4096.0f;                 // normal-range residual
        a[j] = h; b[j] = (_Float16)r;
    }
    *reinterpret_cast<h8*>(h1 + (size_t)gid * 8) = a;
    *reinterpret_cast<h8*>(h2 + (size_t)gid * 8) = b;
}

// ---- W -> split + MFMA-fragment-linear pack, all 4 branches in one launch ----
__device__ __forceinline__
void pack_w_one(const float* __restrict__ W, _Float16* __restrict__ Wp1,
                _Float16* __restrict__ Wp2, int gid)
{
    const int lane = gid & 63;
    const int ni = (gid >> 6) & 3;
    const int ks = (gid >> 8) & 15;
    const int ct = gid >> 12;
    const int col = ct * 64 + ni * 16 + (lane & 15);
    const int k = ks * 32 + (lane >> 4) * 8;
    const float* src = W + (size_t)col * C_ + k;
    h8 a, b;
    #pragma unroll
    for (int j = 0; j < 8; ++j) {
        const float xv = src[j];
        const float hi = (fabsf(xv) >= F16_MIN_NORM) ? xv : 0.0f;
        const _Float16 h = (_Float16)hi;
        const float r = (xv - (float)h) * 4096.0f;
        a[j] = h; b[j] = (_Float16)r;
    }
    *reinterpret_cast<h8*>(Wp1 + (size_t)gid * 8) = a;
    *reinterpret_cast<h8*>(Wp2 + (size_t)gid * 8) = b;
}

__global__ __launch_bounds__(256)
void pack_w_all(const float* __restrict__ Wq, const float* __restrict__ Wk,
                const float* __restrict__ Wv, const float* __restrict__ Wp,
                _Float16* q1, _Float16* q2, _Float16* k1, _Float16* k2,
                _Float16* v1, _Float16* v2, _Float16* p1, _Float16* p2)
{
    const int g = blockIdx.x * 256 + threadIdx.x;     // 131072
    const int br = g >> 15;                            // uniform per block
    const int gid = g & 32767;
    if (br == 0)      pack_w_one(Wq, q1, q2, gid);
    else if (br == 1) pack_w_one(Wk, k1, k2, gid);
    else if (br == 2) pack_w_one(Wv, v1, v2, gid);
    else              pack_w_one(Wp, p1, p2, gid);
}

// ---- gemm3: 512 threads, 8 waves = (tp in {0,1}) x (wr in 0..3) ----
// W staged to LDS in CHUNKS of 4 k-steps (32KB) double-buffered -> barrier
// (and its vmcnt drain) once per 96 wave-MFMAs instead of per 24. Within a
// chunk the 4 k-steps are straight-line: A-loads pipeline under MFMAs.
// LIF t-recurrence crosses the tp split via exact LDS v-state handoff.
__global__ __launch_bounds__(512, 4)
void gemm3_bn_lif(const _Float16* __restrict__ A1p, const _Float16* __restrict__ A2p,
                  const _Float16* __restrict__ Wq1, const _Float16* __restrict__ Wq2,
                  const _Float16* __restrict__ Wk1, const _Float16* __restrict__ Wk2,
                  const _Float16* __restrict__ Wv1, const _Float16* __restrict__ Wv2,
                  const float* __restrict__ biq, const float* __restrict__ gaq,
                  const float* __restrict__ beq, const float* __restrict__ meq,
                  const float* __restrict__ rvq,
                  const float* __restrict__ bik, const float* __restrict__ gak,
                  const float* __restrict__ bek, const float* __restrict__ mek,
                  const float* __restrict__ rvk,
                  const float* __restrict__ biv, const float* __restrict__ gav,
                  const float* __restrict__ bev, const float* __restrict__ mev,
                  const float* __restrict__ rvv,
                  __hip_bfloat16* __restrict__ oq, __hip_bfloat16* __restrict__ ok,
                  __hip_bfloat16* __restrict__ ov)
{
    __shared__ __align__(16) char wsm[65536];           // 2 bufs x 4 ks x 8KB
    const int br = blockIdx.y;                          // uniform
    const _Float16* W1 = (br == 0) ? Wq1 : (br == 1) ? Wk1 : Wv1;
    const _Float16* W2 = (br == 0) ? Wq2 : (br == 1) ? Wk2 : Wv2;
    const float* bias = (br == 0) ? biq : (br == 1) ? bik : biv;
    const float* gam  = (br == 0) ? gaq : (br == 1) ? gak : gav;
    const float* bet  = (br == 0) ? beq : (br == 1) ? bek : bev;
    const float* mea  = (br == 0) ? meq : (br == 1) ? mek : mev;
    const float* rva  = (br == 0) ? rvq : (br == 1) ? rvk : rvv;
    __hip_bfloat16* out = (br == 0) ? oq : (br == 1) ? ok : ov;

    const int id = blockIdx.x;
    const int bt = (id & 7) * 8 + ((id >> 3) & 7);      // XCD-aware swizzle
    const int ct = id >> 6;
    const int tid = threadIdx.x;
    const int wave = tid >> 6, lane = tid & 63;
    const int tp = wave & 1, wr = wave >> 1;
    const int rt = bt * 4 + wr;
    const int row0 = bt * 64, col0 = ct * 64;
    const int lr = lane & 15, lk = lane >> 4;

    f4 accA[2][4], accB[2][4];                          // [ti][ni], t = 2*tp + ti
    #pragma unroll
    for (int ti = 0; ti < 2; ++ti)
        #pragma unroll
        for (int ni = 0; ni < 4; ++ni) { accA[ti][ni] = (f4)0.0f; accB[ti][ni] = (f4)0.0f; }

    const _Float16* aB1 = A1p + (size_t)rt * 32768 + lane * 8;
    const _Float16* aB2 = A2p + (size_t)rt * 32768 + lane * 8;
    // per-wave W staging slot: split s_=wave>>2, frag q_=wave&3 (wave-uniform)
    const int s_ = wave >> 2, q_ = wave & 3;
    const _Float16* wsrc = (s_ ? W2 : W1) + (size_t)ct * 32768 + q_ * 512 + lane * 8;
    const int wdoff = s_ * 4096 + q_ * 1024;

    auto stageChunk = [&](int c, int b) {               // 4 k-steps of W -> LDS
        #pragma unroll
        for (int ksl = 0; ksl < 4; ++ksl) {
            __builtin_amdgcn_global_load_lds(
                (const __attribute__((address_space(1))) unsigned int*)(wsrc + (c * 4 + ksl) * 2048),
                (__attribute__((address_space(3))) unsigned int*)(wsm + b * 32768 + ksl * 8192 + wdoff),
                16, 0, 0);
        }
    };

    stageChunk(0, 0);
    #pragma unroll
    for (int c = 0; c < 4; ++c) {
        const int buf = c & 1;
        __syncthreads();                                // chunk[buf] ready
        if (c < 3) stageChunk(c + 1, buf ^ 1);
        #pragma unroll
        for (int ksl = 0; ksl < 4; ++ksl) {
            const int ks = c * 4 + ksl;
            h8 a1[2], a2[2];
            #pragma unroll
            for (int ti = 0; ti < 2; ++ti) {
                const int t = tp * 2 + ti;
                a1[ti] = *reinterpret_cast<const h8*>(aB1 + (t * 16 + ks) * 512);
                a2[ti] = *reinterpret_cast<const h8*>(aB2 + (t * 16 + ks) * 512);
            }
            const char* wb = wsm + buf * 32768 + ksl * 8192;
            #pragma unroll
            for (int ni = 0; ni < 4; ++ni) {
                const h8 wf1 = *reinterpret_cast<const h8*>(wb + ni * 1024 + lane * 16);
                const h8 wf2 = *reinterpret_cast<const h8*>(wb + 4096 + ni * 1024 + lane * 16);
                #pragma unroll
                for (int ti = 0; ti < 2; ++ti) {
                    accA[ti][ni] = __builtin_amdgcn_mfma_f32_16x16x32_f16(a1[ti], wf1, accA[ti][ni], 0, 0, 0);
                    accB[ti][ni] = __builtin_amdgcn_mfma_f32_16x16x32_f16(a1[ti], wf2, accB[ti][ni], 0, 0, 0);
                    accB[ti][ni] = __builtin_amdgcn_mfma_f32_16x16x32_f16(a2[ti], wf1, accB[ti][ni], 0, 0, 0);
                }
            }
        }
    }

    // ---- BN + LIF epilogue with t-split handoff via LDS ----
    float* vst = (float*)wsm;                           // [64 rows][64 cols] fp32
    float sc[4], bi[4], mn[4], be[4];
    #pragma unroll
    for (int ni = 0; ni < 4; ++ni) {
        const int c = col0 + ni * 16 + lr;
        sc[ni] = gam[c] * (1.0f / sqrtf(rva[c] + EPSf));
        bi[ni] = bias[c]; mn[ni] = mea[c]; be[ni] = bet[c];
    }
    __syncthreads();                                    // all W-buffer reads done
    if (tp == 0) {
        #pragma unroll
        for (int ni = 0; ni < 4; ++ni)
            #pragma unroll
            for (int r = 0; r < 4; ++r) {
                const int rl = wr * 16 + lk * 4 + r;    // local row 0..63
                const int bn = row0 + rl;
                float vm = 0.0f;
                #pragma unroll
                for (int ti = 0; ti < 2; ++ti) {        // t = 0,1
                    const float res = accA[ti][ni][r] + INV4096 * accB[ti][ni][r];
                    const float y = ((res + bi[ni]) - mn[ni]) * sc[ni] + be[ni];
                    vm = vm + (y - vm) * 0.5f;
                    const float s = (vm >= 1.0f) ? 1.0f : 0.0f;
                    vm = (s != 0.0f) ? 0.0f : vm;
                    const int b = bn >> 9, n = bn & 511;
                    out[((((size_t)ti * B_ + b) * H_ + ct) * N_ + n) * D_ + ni * 16 + lr] =
                        __float2bfloat16(s);
                }
                vst[rl * 64 + ni * 16 + lr] = vm;       // exact v after t=1
            }
    }
    __syncthreads();
    if (tp == 1) {
        #pragma unroll
        for (int ni = 0; ni < 4; ++ni)
            #pragma unroll
            for (int r = 0; r < 4; ++r) {
                const int rl = wr * 16 + lk * 4 + r;
                const int bn = row0 + rl;
                float vm = vst[rl * 64 + ni * 16 + lr];
                #pragma unroll
                for (int ti = 0; ti < 2; ++ti) {        // t = 2,3
                    const float res = accA[ti][ni][r] + INV4096 * accB[ti][ni][r];
                    const float y = ((res + bi[ni]) - mn[ni]) * sc[ni] + be[ni];
                    vm = vm + (y - vm) * 0.5f;
                    const float s = (vm >= 1.0f) ? 1.0f : 0.0f;
                    vm = (s != 0.0f) ? 0.0f : vm;
                    const int b = bn >> 9, n = bn & 511;
                    out[((((size_t)(2 + ti) * B_ + b) * H_ + ct) * N_ + n) * D_ + ni * 16 + lr] =
                        __float2bfloat16(s);
                }
            }
    }
}

// ---- p-GEMM, same chunked structure: A = exact f16 spikes (packed, 1 term) ----
__global__ __launch_bounds__(512, 4)
void gemm_p_bn_lif(const _Float16* __restrict__ A1p,
                   const _Float16* __restrict__ Wp1, const _Float16* __restrict__ Wp2,
                   const float* __restrict__ bias, const float* __restrict__ gam,
                   const float* __restrict__ bet, const float* __restrict__ mea,
                   const float* __restrict__ rva, float* __restrict__ out_plain)
{
    __shared__ __align__(16) char wsm[65536];
    const int id = blockIdx.x;
    const int bt = (id & 7) * 8 + ((id >> 3) & 7);
    const int ct = id >> 6;
    const int tid = threadIdx.x;
    const int wave = tid >> 6, lane = tid & 63;
    const int tp = wave & 1, wr = wave >> 1;
    const int rt = bt * 4 + wr;
    const int row0 = bt * 64, col0 = ct * 64;
    const int lr = lane & 15, lk = lane >> 4;

    f4 accA[2][4], accB[2][4];
    #pragma unroll
    for (int ti = 0; ti < 2; ++ti)
        #pragma unroll
        for (int ni = 0; ni < 4; ++ni) { accA[ti][ni] = (f4)0.0f; accB[ti][ni] = (f4)0.0f; }

    const _Float16* aB1 = A1p + (size_t)rt * 32768 + lane * 8;
    const int s_ = wave >> 2, q_ = wave & 3;
    const _Float16* wsrc = (s_ ? Wp2 : Wp1) + (size_t)ct * 32768 + q_ * 512 + lane * 8;
    const int wdoff = s_ * 4096 + q_ * 1024;

    auto stageChunk = [&](int c, int b) {
        #pragma unroll
        for (int ksl = 0; ksl < 4; ++ksl) {
            __builtin_amdgcn_global_load_lds(
                (const __attribute__((address_space(1))) unsigned int*)(wsrc + (c * 4 + ksl) * 2048),
                (__attribute__((address_space(3))) unsigned int*)(wsm + b * 32768 + ksl * 8192 + wdoff),
                16, 0, 0);
        }
    };

    stageChunk(0, 0);
    #pragma unroll
    for (int c = 0; c < 4; ++c) {
        const int buf = c & 1;
        __syncthreads();
        if (c < 3) stageChunk(c + 1, buf ^ 1);
        #pragma unroll
        for (int ksl = 0; ksl < 4; ++ksl) {
            const int ks = c * 4 + ksl;
            h8 a1[2];
            #pragma unroll
            for (int ti = 0; ti < 2; ++ti) {
                const int t = tp * 2 + ti;
                a1[ti] = *reinterpret_cast<const h8*>(aB1 + (t * 16 + ks) * 512);
            }
            const char* wb = wsm + buf * 32768 + ksl * 8192;
            #pragma unroll
            for (int ni = 0; ni < 4; ++ni) {
                const h8 wf1 = *reinterpret_cast<const h8*>(wb + ni * 1024 + lane * 16);
                const h8 wf2 = *reinterpret_cast<const h8*>(wb + 4096 + ni * 1024 + lane * 16);
                #pragma unroll
                for (int ti = 0; ti < 2; ++ti) {
                    accA[ti][ni] = __builtin_amdgcn_mfma_f32_16x16x32_f16(a1[ti], wf1, accA[ti][ni], 0, 0, 0);
                    accB[ti][ni] = __builtin_amdgcn_mfma_f32_16x16x32_f16(a1[ti], wf2, accB[ti][ni], 0, 0, 0);
                }
            }
        }
    }

    float* vst = (float*)wsm;
    float sc[4], bi[4], mn[4], be[4];
    #pragma unroll
    for (int ni = 0; ni < 4; ++ni) {
        const int c = col0 + ni * 16 + lr;
        sc[ni] = gam[c] * (1.0f / sqrtf(rva[c] + EPSf));
        bi[ni] = bias[c]; mn[ni] = mea[c]; be[ni] = bet[c];
    }
    __syncthreads();
    if (tp == 0) {
        #pragma unroll
        for (int ni = 0; ni < 4; ++ni)
            #pragma unroll
            for (int r = 0; r < 4; ++r) {
                const int rl = wr * 16 + lk * 4 + r;
                const int bn = row0 + rl;
                float vm = 0.0f;
                #pragma unroll
                for (int ti = 0; ti < 2; ++ti) {        // t = 0,1
                    const float res = accA[ti][ni][r] + INV4096 * accB[ti][ni][r];
                    const float y = ((res + bi[ni]) - mn[ni]) * sc[ni] + be[ni];
                    vm = vm + (y - vm) * 0.5f;
                    const float s = (vm >= 1.0f) ? 1.0f : 0.0f;
                    vm = (s != 0.0f) ? 0.0f : vm;
                    out_plain[((size_t)ti * BNR + bn) * C_ + col0 + ni * 16 + lr] = s;
                }
                vst[rl * 64 + ni * 16 + lr] = vm;
            }
    }
    __syncthreads();
    if (tp == 1) {
        #pragma unroll
        for (int ni = 0; ni < 4; ++ni)
            #pragma unroll
            for (int r = 0; r < 4; ++r) {
                const int rl = wr * 16 + lk * 4 + r;
                const int bn = row0 + rl;
                float vm = vst[rl * 64 + ni * 16 + lr];
                #pragma unroll
                for (int ti = 0; ti < 2; ++ti) {        // t = 2,3
                    const float res = accA[ti][ni][r] + INV4096 * accB[ti][ni][r];
                    const float y = ((res + bi[ni]) - mn[ni]) * sc[ni] + be[ni];
                    vm = vm + (y - vm) * 0.5f;
                    const float s = (vm >= 1.0f) ? 1.0f : 0.0f;
                    vm = (s != 0.0f) ? 0.0f : vm;
                    out_plain[((size_t)(2 + ti) * BNR + bn) * C_ + col0 + ni * 16 + lr] = s;
                }
            }
    }
}

// ---- kv[d1][d2] = sum_n k[n,d1]*v[n,d2] per (t,b,h) ----
__global__ __launch_bounds__(256)
void ktv_kernel(const __hip_bfloat16* __restrict__ sk, const __hip_bfloat16* __restrict__ sv,
                float* __restrict__ kv)
{
    __shared__ __hip_bfloat16 kl[64][64];
    __shared__ __hip_bfloat16 vl[64][64];
    const int tbh = blockIdx.x;
    const int tid = threadIdx.x;
    const int tx = tid & 15, ty = tid >> 4;
    const size_t base = (size_t)tbh * N_ * D_;
    float acc[4][4] = {};
    for (int n0 = 0; n0 < N_; n0 += 64) {
        __syncthreads();
        #pragma unroll
        for (int p = 0; p < 2; ++p) {
            const int idx = tid + p * 256;
            const int r = idx >> 3, c8 = (idx & 7) * 8;
            *reinterpret_cast<float4*>(&kl[r][c8]) =
                *reinterpret_cast<const float4*>(&sk[base + (size_t)(n0 + r) * D_ + c8]);
            *reinterpret_cast<float4*>(&vl[r][c8]) =
                *reinterpret_cast<const float4*>(&sv[base + (size_t)(n0 + r) * D_ + c8]);
        }
        __syncthreads();
        for (int nn = 0; nn < 64; ++nn) {
            float a[4], b[4];
            #pragma unroll
            for (int i = 0; i < 4; ++i) a[i] = __bfloat162float(kl[nn][ty * 4 + i]);
            #pragma unroll
            for (int j = 0; j < 4; ++j) b[j] = __bfloat162float(vl[nn][tx * 4 + j]);
            #pragma unroll
            for (int i = 0; i < 4; ++i)
                #pragma unroll
                for (int j = 0; j < 4; ++j)
                    acc[i][j] = fmaf(a[i], b[j], acc[i][j]);
        }
    }
    float* out = kv + (size_t)tbh * 4096;
    #pragma unroll
    for (int i = 0; i < 4; ++i)
        #pragma unroll
        for (int j = 0; j < 4; ++j)
            out[(ty * 4 + i) * 64 + tx * 4 + j] = acc[i][j];
}

// ---- o = 0.125 * q @ kv, fused attn-LIF (vth=0.5); writes packed f16 spikes ----
__global__ __launch_bounds__(256)
void qkv_lif_kernel(const __hip_bfloat16* __restrict__ sq, const float* __restrict__ kv,
                    _Float16* __restrict__ osp)
{
    __shared__ float kvl[64][64];
    __shared__ __hip_bfloat16 ql[64][64];
    const int nt = blockIdx.x, b = blockIdx.y, h = blockIdx.z;
    const int tid = threadIdx.x;
    const int tx = tid & 15, ty = tid >> 4;
    const int n0 = nt * 64;
    float v[4][4] = {};
    for (int t = 0; t < T_; ++t) {
        const int tbh = (t * B_ + b) * H_ + h;
        __syncthreads();
        #pragma unroll
        for (int p = 0; p < 16; ++p) {
            const int idx = p * 256 + tid;
            kvl[idx >> 6][idx & 63] = kv[(size_t)tbh * 4096 + idx];
        }
        #pragma unroll
        for (int p = 0; p < 2; ++p) {
            const int idx = tid + p * 256;
            const int r = idx >> 3, c8 = (idx & 7) * 8;
            *reinterpret_cast<float4*>(&ql[r][c8]) =
                *reinterpret_cast<const float4*>(&sq[((size_t)tbh * N_ + n0 + r) * D_ + c8]);
        }
        __syncthreads();
        float acc[4][4] = {};
        for (int dd = 0; dd < 64; ++dd) {
            float a[4], bb[4];
            #pragma unroll
            for (int i = 0; i < 4; ++i) a[i] = __bfloat162float(ql[ty * 4 + i][dd]);
            #pragma unroll
            for (int j = 0; j < 4; ++j) bb[j] = kvl[dd][tx * 4 + j];
            #pragma unroll
            for (int i = 0; i < 4; ++i)
                #pragma unroll
                for (int j = 0; j < 4; ++j)
                    acc[i][j] = fmaf(a[i], bb[j], acc[i][j]);
        }
        #pragma unroll
        for (int i = 0; i < 4; ++i) {
            const int row_bn = b * N_ + n0 + ty * 4 + i;
            const int c0 = h * 64 + tx * 4;
            const int rt = row_bn >> 4, rlo = row_bn & 15;
            const int ks = c0 >> 5, lk3 = (c0 >> 3) & 3, j0 = c0 & 7;
            h4v sp;
            #pragma unroll
            for (int j = 0; j < 4; ++j) {
                const float y = 0.125f * acc[i][j];     // exact (integer counts)
                float vv = v[i][j];
                vv = vv + (y - vv) * 0.5f;
                const float s = (vv >= 0.5f) ? 1.0f : 0.0f;
                sp[j] = (_Float16)s;
                v[i][j] = (s != 0.0f) ? 0.0f : vv;
            }
            _Float16* dst = osp + ((((size_t)rt * 4 + t) * 16 + ks) * 64 + lk3 * 16 + rlo) * 8 + j0;
            *reinterpret_cast<h4v*>(dst) = sp;
        }
    }
}

extern "C" void kernel_launch(void* const* d_in, const int* in_sizes, int n_in,
                              void* d_out, int out_size, void* d_ws, size_t ws_size,
                              hipStream_t stream)
{
    const float* x = (const float*)d_in[0];
    const float *W[4], *bia[4], *gam[4], *bet[4], *mea[4], *rva[4];
    for (int br = 0; br < 4; ++br) {
        W[br]   = (const float*)d_in[1 + 6 * br + 0];
        bia[br] = (const float*)d_in[1 + 6 * br + 1];
        gam[br] = (const float*)d_in[1 + 6 * br + 2];
        bet[br] = (const float*)d_in[1 + 6 * br + 3];
        mea[br] = (const float*)d_in[1 + 6 * br + 4];
        rva[br] = (const float*)d_in[1 + 6 * br + 5];
    }
    char* ws = (char*)d_ws;
    _Float16* x1 = (_Float16*)(ws + 0);
    _Float16* x2 = (_Float16*)(ws + 16777216);
    __hip_bfloat16* sq = (__hip_bfloat16*)(ws + 33554432);
    __hip_bfloat16* sk = (__hip_bfloat16*)(ws + 50331648);
    __hip_bfloat16* sv = (__hip_bfloat16*)(ws + 67108864);
    _Float16* w1[4], *w2[4];
    for (int br = 0; br < 4; ++br) {
        w1[br] = (_Float16*)(ws + 83886080 + (size_t)br * 1048576);
        w2[br] = (_Float16*)(ws + 83886080 + (size_t)br * 1048576 + 524288);
    }
    float*    kv  = (float*)(ws + 16777216);     // aliases x2 (dead after gemm3)
    _Float16* osp = (_Float16*)(ws + 0);         // aliases x1 (dead after gemm3)

    dim3 blk(256);
    split_pack_x<<<dim3(4096), blk, 0, stream>>>(x, x1, x2);
    pack_w_all<<<dim3(512), blk, 0, stream>>>(W[0], W[1], W[2], W[3],
        w1[0], w2[0], w1[1], w2[1], w1[2], w2[2], w1[3], w2[3]);

    gemm3_bn_lif<<<dim3(512, 3), dim3(512), 0, stream>>>(x1, x2,
        w1[0], w2[0], w1[1], w2[1], w1[2], w2[2],
        bia[0], gam[0], bet[0], mea[0], rva[0],
        bia[1], gam[1], bet[1], mea[1], rva[1],
        bia[2], gam[2], bet[2], mea[2], rva[2],
        sq, sk, sv);

    ktv_kernel<<<dim3(T_ * B_ * H_), blk, 0, stream>>>(sk, sv, kv);
    qkv_lif_kernel<<<dim3(N_ / 64, B_, H_), blk, 0, stream>>>(sq, kv, osp);

    gemm_p_bn_lif<<<dim3(512), dim3(512), 0, stream>>>(osp, w1[3], w2[3],
        bia[3], gam[3], bet[3], mea[3], rva[3], (float*)d_out);
}

// Round 11
// 167.406 us; speedup vs baseline: 3.3942x; 1.0442x over previous
//
#include <hip/hip_runtime.h>
#include <hip/hip_bf16.h>

typedef _Float16 h8 __attribute__((ext_vector_type(8)));
typedef float f4 __attribute__((ext_vector_type(4)));

#define T_ 4
#define B_ 8
#define N_ 512
#define C_ 512
#define H_ 8
#define D_ 64
#define BNR 4096
#define EPSf 1e-5f
#define F16_MIN_NORM 6.1035156e-05f
#define INV4096 0.000244140625f

// ---- x -> (h1 + 2^-12 * h2) f16 split, packed MFMA-fragment-linear ----
__global__ __launch_bounds__(256)
void split_pack_x(const float* __restrict__ in, _Float16* __restrict__ h1,
                  _Float16* __restrict__ h2)
{
    const int gid = blockIdx.x * 256 + threadIdx.x;    // 1048576 h8-groups
    const int lane = gid & 63;
    const int ks = (gid >> 6) & 15;
    const int t = (gid >> 10) & 3;
    const int rt = gid >> 12;
    const int row = rt * 16 + (lane & 15);
    const size_t src = ((size_t)t * BNR + row) * C_ + ks * 32 + (lane >> 4) * 8;
    const float4 x0 = *reinterpret_cast<const float4*>(in + src);
    const float4 x1 = *reinterpret_cast<const float4*>(in + src + 4);
    h8 a, b;
    #pragma unroll
    for (int j = 0; j < 8; ++j) {
        const float xv = (j < 4) ? (&x0.x)[j] : (&x1.x)[j - 4];
        const float hi = (fabsf(xv) >= F16_MIN_NORM) ? xv : 0.0f;
        const _Float16 h = (_Float16)hi;
        const float r = (xv - (float)h) * 4096.0f;
        a[j] = h; b[j] = (_Float16)r;
    }
    *reinterpret_cast<h8*>(h1 + (size_t)gid * 8) = a;
    *reinterpret_cast<h8*>(h2 + (size_t)gid * 8) = b;
}

// ---- W -> split + MFMA-fragment-linear pack ----
__device__ __forceinline__
void pack_w_one(const float* __restrict__ W, _Float16* __restrict__ Wp1,
                _Float16* __restrict__ Wp2, int gid)
{
    const int lane = gid & 63;
    const int ni = (gid >> 6) & 3;
    const int ks = (gid >> 8) & 15;
    const int ct = gid >> 12;
    const int col = ct * 64 + ni * 16 + (lane & 15);
    const int k = ks * 32 + (lane >> 4) * 8;
    const float* src = W + (size_t)col * C_ + k;
    h8 a, b;
    #pragma unroll
    for (int j = 0; j < 8; ++j) {
        const float xv = src[j];
        const float hi = (fabsf(xv) >= F16_MIN_NORM) ? xv : 0.0f;
        const _Float16 h = (_Float16)hi;
        const float r = (xv - (float)h) * 4096.0f;
        a[j] = h; b[j] = (_Float16)r;
    }
    *reinterpret_cast<h8*>(Wp1 + (size_t)gid * 8) = a;
    *reinterpret_cast<h8*>(Wp2 + (size_t)gid * 8) = b;
}

__global__ __launch_bounds__(256)
void pack_w_all(const float* __restrict__ Wq, const float* __restrict__ Wk,
                const float* __restrict__ Wv, const float* __restrict__ Wp,
                _Float16* q1, _Float16* q2, _Float16* k1, _Float16* k2,
                _Float16* v1, _Float16* v2, _Float16* p1, _Float16* p2)
{
    const int g = blockIdx.x * 256 + threadIdx.x;     // 131072
    const int br = g >> 15;
    const int gid = g & 32767;
    if (br == 0)      pack_w_one(Wq, q1, q2, gid);
    else if (br == 1) pack_w_one(Wk, k1, k2, gid);
    else if (br == 2) pack_w_one(Wv, v1, v2, gid);
    else              pack_w_one(Wp, p1, p2, gid);
}

// ---- gemm3 (r9 structure, measured best): 512 thr, 8 waves = (tp) x (wr) ----
// W staged per-k-step to 16KB LDS dbuf; A direct fragment-packed; LIF t-split
// handoff via LDS v-state. Outputs f16 spikes (exact 0/1).
__global__ __launch_bounds__(512, 4)
void gemm3_bn_lif(const _Float16* __restrict__ A1p, const _Float16* __restrict__ A2p,
                  const _Float16* __restrict__ Wq1, const _Float16* __restrict__ Wq2,
                  const _Float16* __restrict__ Wk1, const _Float16* __restrict__ Wk2,
                  const _Float16* __restrict__ Wv1, const _Float16* __restrict__ Wv2,
                  const float* __restrict__ biq, const float* __restrict__ gaq,
                  const float* __restrict__ beq, const float* __restrict__ meq,
                  const float* __restrict__ rvq,
                  const float* __restrict__ bik, const float* __restrict__ gak,
                  const float* __restrict__ bek, const float* __restrict__ mek,
                  const float* __restrict__ rvk,
                  const float* __restrict__ biv, const float* __restrict__ gav,
                  const float* __restrict__ bev, const float* __restrict__ mev,
                  const float* __restrict__ rvv,
                  _Float16* __restrict__ oq, _Float16* __restrict__ ok,
                  _Float16* __restrict__ ov)
{
    __shared__ __align__(16) char wsm[16384];           // 2 x 8KB W dbuf; reused as v-state
    const int br = blockIdx.y;
    const _Float16* W1 = (br == 0) ? Wq1 : (br == 1) ? Wk1 : Wv1;
    const _Float16* W2 = (br == 0) ? Wq2 : (br == 1) ? Wk2 : Wv2;
    const float* bias = (br == 0) ? biq : (br == 1) ? bik : biv;
    const float* gam  = (br == 0) ? gaq : (br == 1) ? gak : gav;
    const float* bet  = (br == 0) ? beq : (br == 1) ? bek : bev;
    const float* mea  = (br == 0) ? meq : (br == 1) ? mek : mev;
    const float* rva  = (br == 0) ? rvq : (br == 1) ? rvk : rvv;
    _Float16* out = (br == 0) ? oq : (br == 1) ? ok : ov;

    const int id = blockIdx.x;
    const int bt = (id & 7) * 8 + ((id >> 3) & 7);      // XCD-aware swizzle
    const int ct = id >> 6;
    const int tid = threadIdx.x;
    const int wave = tid >> 6, lane = tid & 63;
    const int tp = wave & 1, wr = wave >> 1;
    const int rt = bt * 4 + wr;
    const int row0 = bt * 64, col0 = ct * 64;
    const int lr = lane & 15, lk = lane >> 4;

    f4 accA[2][4], accB[2][4];
    #pragma unroll
    for (int ti = 0; ti < 2; ++ti)
        #pragma unroll
        for (int ni = 0; ni < 4; ++ni) { accA[ti][ni] = (f4)0.0f; accB[ti][ni] = (f4)0.0f; }

    const _Float16* aB1 = A1p + (size_t)rt * 32768 + lane * 8;
    const _Float16* aB2 = A2p + (size_t)rt * 32768 + lane * 8;
    const int s_ = wave >> 2, q_ = wave & 3;
    const _Float16* wsrc = (s_ ? W2 : W1) + (size_t)ct * 32768 + q_ * 512 + lane * 8;
    const int wdoff = s_ * 4096 + q_ * 1024;

    auto stageW = [&](int ks, int b) {
        __builtin_amdgcn_global_load_lds(
            (const __attribute__((address_space(1))) unsigned int*)(wsrc + ks * 2048),
            (__attribute__((address_space(3))) unsigned int*)(wsm + b * 8192 + wdoff),
            16, 0, 0);
    };

    stageW(0, 0);
    #pragma unroll 2
    for (int ks = 0; ks < 16; ++ks) {
        const int buf = ks & 1;
        __syncthreads();
        if (ks < 15) stageW(ks + 1, buf ^ 1);
        h8 a1[2], a2[2];
        #pragma unroll
        for (int ti = 0; ti < 2; ++ti) {
            const int t = tp * 2 + ti;
            a1[ti] = *reinterpret_cast<const h8*>(aB1 + (t * 16 + ks) * 512);
            a2[ti] = *reinterpret_cast<const h8*>(aB2 + (t * 16 + ks) * 512);
        }
        const char* wb = wsm + buf * 8192;
        #pragma unroll
        for (int ni = 0; ni < 4; ++ni) {
            const h8 wf1 = *reinterpret_cast<const h8*>(wb + ni * 1024 + lane * 16);
            const h8 wf2 = *reinterpret_cast<const h8*>(wb + 4096 + ni * 1024 + lane * 16);
            #pragma unroll
            for (int ti = 0; ti < 2; ++ti) {
                accA[ti][ni] = __builtin_amdgcn_mfma_f32_16x16x32_f16(a1[ti], wf1, accA[ti][ni], 0, 0, 0);
                accB[ti][ni] = __builtin_amdgcn_mfma_f32_16x16x32_f16(a1[ti], wf2, accB[ti][ni], 0, 0, 0);
                accB[ti][ni] = __builtin_amdgcn_mfma_f32_16x16x32_f16(a2[ti], wf1, accB[ti][ni], 0, 0, 0);
            }
        }
    }

    // ---- BN + LIF epilogue with t-split handoff via LDS ----
    float* vst = (float*)wsm;
    float sc[4], bi[4], mn[4], be[4];
    #pragma unroll
    for (int ni = 0; ni < 4; ++ni) {
        const int c = col0 + ni * 16 + lr;
        sc[ni] = gam[c] * (1.0f / sqrtf(rva[c] + EPSf));
        bi[ni] = bias[c]; mn[ni] = mea[c]; be[ni] = bet[c];
    }
    __syncthreads();
    if (tp == 0) {
        #pragma unroll
        for (int ni = 0; ni < 4; ++ni)
            #pragma unroll
            for (int r = 0; r < 4; ++r) {
                const int rl = wr * 16 + lk * 4 + r;
                const int bn = row0 + rl;
                float vm = 0.0f;
                #pragma unroll
                for (int ti = 0; ti < 2; ++ti) {        // t = 0,1
                    const float res = accA[ti][ni][r] + INV4096 * accB[ti][ni][r];
                    const float y = ((res + bi[ni]) - mn[ni]) * sc[ni] + be[ni];
                    vm = vm + (y - vm) * 0.5f;
                    const float s = (vm >= 1.0f) ? 1.0f : 0.0f;
                    vm = (s != 0.0f) ? 0.0f : vm;
                    const int b = bn >> 9, n = bn & 511;
                    out[((((size_t)ti * B_ + b) * H_ + ct) * N_ + n) * D_ + ni * 16 + lr] =
                        (_Float16)s;
                }
                vst[rl * 64 + ni * 16 + lr] = vm;
            }
    }
    __syncthreads();
    if (tp == 1) {
        #pragma unroll
        for (int ni = 0; ni < 4; ++ni)
            #pragma unroll
            for (int r = 0; r < 4; ++r) {
                const int rl = wr * 16 + lk * 4 + r;
                const int bn = row0 + rl;
                float vm = vst[rl * 64 + ni * 16 + lr];
                #pragma unroll
                for (int ti = 0; ti < 2; ++ti) {        // t = 2,3
                    const float res = accA[ti][ni][r] + INV4096 * accB[ti][ni][r];
                    const float y = ((res + bi[ni]) - mn[ni]) * sc[ni] + be[ni];
                    vm = vm + (y - vm) * 0.5f;
                    const float s = (vm >= 1.0f) ? 1.0f : 0.0f;
                    vm = (s != 0.0f) ? 0.0f : vm;
                    const int b = bn >> 9, n = bn & 511;
                    out[((((size_t)(2 + ti) * B_ + b) * H_ + ct) * N_ + n) * D_ + ni * 16 + lr] =
                        (_Float16)s;
                }
            }
    }
}

// ---- p-GEMM (r10 chunked structure, measured good) ----
__global__ __launch_bounds__(512, 4)
void gemm_p_bn_lif(const _Float16* __restrict__ A1p,
                   const _Float16* __restrict__ Wp1, const _Float16* __restrict__ Wp2,
                   const float* __restrict__ bias, const float* __restrict__ gam,
                   const float* __restrict__ bet, const float* __restrict__ mea,
                   const float* __restrict__ rva, float* __restrict__ out_plain)
{
    __shared__ __align__(16) char wsm[65536];
    const int id = blockIdx.x;
    const int bt = (id & 7) * 8 + ((id >> 3) & 7);
    const int ct = id >> 6;
    const int tid = threadIdx.x;
    const int wave = tid >> 6, lane = tid & 63;
    const int tp = wave & 1, wr = wave >> 1;
    const int rt = bt * 4 + wr;
    const int row0 = bt * 64, col0 = ct * 64;
    const int lr = lane & 15, lk = lane >> 4;

    f4 accA[2][4], accB[2][4];
    #pragma unroll
    for (int ti = 0; ti < 2; ++ti)
        #pragma unroll
        for (int ni = 0; ni < 4; ++ni) { accA[ti][ni] = (f4)0.0f; accB[ti][ni] = (f4)0.0f; }

    const _Float16* aB1 = A1p + (size_t)rt * 32768 + lane * 8;
    const int s_ = wave >> 2, q_ = wave & 3;
    const _Float16* wsrc = (s_ ? Wp2 : Wp1) + (size_t)ct * 32768 + q_ * 512 + lane * 8;
    const int wdoff = s_ * 4096 + q_ * 1024;

    auto stageChunk = [&](int c, int b) {
        #pragma unroll
        for (int ksl = 0; ksl < 4; ++ksl) {
            __builtin_amdgcn_global_load_lds(
                (const __attribute__((address_space(1))) unsigned int*)(wsrc + (c * 4 + ksl) * 2048),
                (__attribute__((address_space(3))) unsigned int*)(wsm + b * 32768 + ksl * 8192 + wdoff),
                16, 0, 0);
        }
    };

    stageChunk(0, 0);
    #pragma unroll
    for (int c = 0; c < 4; ++c) {
        const int buf = c & 1;
        __syncthreads();
        if (c < 3) stageChunk(c + 1, buf ^ 1);
        #pragma unroll
        for (int ksl = 0; ksl < 4; ++ksl) {
            const int ks = c * 4 + ksl;
            h8 a1[2];
            #pragma unroll
            for (int ti = 0; ti < 2; ++ti) {
                const int t = tp * 2 + ti;
                a1[ti] = *reinterpret_cast<const h8*>(aB1 + (t * 16 + ks) * 512);
            }
            const char* wb = wsm + buf * 32768 + ksl * 8192;
            #pragma unroll
            for (int ni = 0; ni < 4; ++ni) {
                const h8 wf1 = *reinterpret_cast<const h8*>(wb + ni * 1024 + lane * 16);
                const h8 wf2 = *reinterpret_cast<const h8*>(wb + 4096 + ni * 1024 + lane * 16);
                #pragma unroll
                for (int ti = 0; ti < 2; ++ti) {
                    accA[ti][ni] = __builtin_amdgcn_mfma_f32_16x16x32_f16(a1[ti], wf1, accA[ti][ni], 0, 0, 0);
                    accB[ti][ni] = __builtin_amdgcn_mfma_f32_16x16x32_f16(a1[ti], wf2, accB[ti][ni], 0, 0, 0);
                }
            }
        }
    }

    float* vst = (float*)wsm;
    float sc[4], bi[4], mn[4], be[4];
    #pragma unroll
    for (int ni = 0; ni < 4; ++ni) {
        const int c = col0 + ni * 16 + lr;
        sc[ni] = gam[c] * (1.0f / sqrtf(rva[c] + EPSf));
        bi[ni] = bias[c]; mn[ni] = mea[c]; be[ni] = bet[c];
    }
    __syncthreads();
    if (tp == 0) {
        #pragma unroll
        for (int ni = 0; ni < 4; ++ni)
            #pragma unroll
            for (int r = 0; r < 4; ++r) {
                const int rl = wr * 16 + lk * 4 + r;
                const int bn = row0 + rl;
                float vm = 0.0f;
                #pragma unroll
                for (int ti = 0; ti < 2; ++ti) {        // t = 0,1
                    const float res = accA[ti][ni][r] + INV4096 * accB[ti][ni][r];
                    const float y = ((res + bi[ni]) - mn[ni]) * sc[ni] + be[ni];
                    vm = vm + (y - vm) * 0.5f;
                    const float s = (vm >= 1.0f) ? 1.0f : 0.0f;
                    vm = (s != 0.0f) ? 0.0f : vm;
                    out_plain[((size_t)ti * BNR + bn) * C_ + col0 + ni * 16 + lr] = s;
                }
                vst[rl * 64 + ni * 16 + lr] = vm;
            }
    }
    __syncthreads();
    if (tp == 1) {
        #pragma unroll
        for (int ni = 0; ni < 4; ++ni)
            #pragma unroll
            for (int r = 0; r < 4; ++r) {
                const int rl = wr * 16 + lk * 4 + r;
                const int bn = row0 + rl;
                float vm = vst[rl * 64 + ni * 16 + lr];
                #pragma unroll
                for (int ti = 0; ti < 2; ++ti) {        // t = 2,3
                    const float res = accA[ti][ni][r] + INV4096 * accB[ti][ni][r];
                    const float y = ((res + bi[ni]) - mn[ni]) * sc[ni] + be[ni];
                    vm = vm + (y - vm) * 0.5f;
                    const float s = (vm >= 1.0f) ? 1.0f : 0.0f;
                    vm = (s != 0.0f) ? 0.0f : vm;
                    out_plain[((size_t)(2 + ti) * BNR + bn) * C_ + col0 + ni * 16 + lr] = s;
                }
            }
    }
}

// ---- kvT[d2][d1] = sum_n k[n,d1]*v[n,d2] per (t,b,h); f16 exact (ints <= 512) ----
__global__ __launch_bounds__(256)
void ktv_kernel(const _Float16* __restrict__ sk, const _Float16* __restrict__ sv,
                _Float16* __restrict__ kvT)
{
    __shared__ _Float16 kl[64][64];
    __shared__ _Float16 vl[64][64];
    const int tbh = blockIdx.x;
    const int tid = threadIdx.x;
    const int tx = tid & 15, ty = tid >> 4;
    const size_t base = (size_t)tbh * N_ * D_;
    float acc[4][4] = {};
    for (int n0 = 0; n0 < N_; n0 += 64) {
        __syncthreads();
        #pragma unroll
        for (int p = 0; p < 2; ++p) {
            const int idx = tid + p * 256;
            const int r = idx >> 3, c8 = (idx & 7) * 8;
            *reinterpret_cast<float4*>(&kl[r][c8]) =
                *reinterpret_cast<const float4*>(&sk[base + (size_t)(n0 + r) * D_ + c8]);
            *reinterpret_cast<float4*>(&vl[r][c8]) =
                *reinterpret_cast<const float4*>(&sv[base + (size_t)(n0 + r) * D_ + c8]);
        }
        __syncthreads();
        for (int nn = 0; nn < 64; ++nn) {
            float a[4], b[4];
            #pragma unroll
            for (int i = 0; i < 4; ++i) a[i] = (float)kl[nn][ty * 4 + i];
            #pragma unroll
            for (int j = 0; j < 4; ++j) b[j] = (float)vl[nn][tx * 4 + j];
            #pragma unroll
            for (int i = 0; i < 4; ++i)
                #pragma unroll
                for (int j = 0; j < 4; ++j)
                    acc[i][j] = fmaf(a[i], b[j], acc[i][j]);
        }
    }
    _Float16* out = kvT + (size_t)tbh * 4096;           // [d2][d1] (transposed)
    #pragma unroll
    for (int i = 0; i < 4; ++i)
        #pragma unroll
        for (int j = 0; j < 4; ++j)
            out[(tx * 4 + j) * 64 + ty * 4 + i] = (_Float16)acc[i][j];
}

// ---- o = 0.125 * q @ kv via MFMA (exact integer arith), fused attn-LIF ----
// Block (nt,b,h), 4 waves; wave wv owns rows [n0+16wv,+16). Both frags direct
// from global. Per-wave XOR-swizzled LDS tile transposes MFMA C-layout into
// the packed-fragment layout (coalesced 1KB stores). No cross-wave deps -> no barriers.
__global__ __launch_bounds__(256)
void qkv_mfma_lif(const _Float16* __restrict__ sq, const _Float16* __restrict__ kvT,
                  _Float16* __restrict__ osp)
{
    __shared__ __align__(16) char ot[8192];             // [64 rows][128B], swizzled
    const int nt = blockIdx.x, b = blockIdx.y, h = blockIdx.z;
    const int tid = threadIdx.x;
    const int wv = tid >> 6, lane = tid & 63;
    const int lr = lane & 15, lk = lane >> 4;
    const int n0 = nt * 64;

    f4 vst[4];
    #pragma unroll
    for (int ni = 0; ni < 4; ++ni) vst[ni] = (f4)0.0f;

    for (int t = 0; t < T_; ++t) {
        const int tbh = (t * B_ + b) * H_ + h;
        const _Float16* qb = sq + ((size_t)tbh * N_ + n0 + wv * 16 + lr) * D_;
        const h8 a0 = *reinterpret_cast<const h8*>(qb + lk * 8);
        const h8 a1 = *reinterpret_cast<const h8*>(qb + 32 + lk * 8);
        const _Float16* kb = kvT + (size_t)tbh * 4096 + lr * 64 + lk * 8;
        f4 acc[4];
        #pragma unroll
        for (int ni = 0; ni < 4; ++ni) {
            const _Float16* kbn = kb + ni * 1024;       // +ni*16 rows
            const h8 b0 = *reinterpret_cast<const h8*>(kbn);
            const h8 b1 = *reinterpret_cast<const h8*>(kbn + 32);
            f4 a = (f4)0.0f;
            a = __builtin_amdgcn_mfma_f32_16x16x32_f16(a0, b0, a, 0, 0, 0);
            a = __builtin_amdgcn_mfma_f32_16x16x32_f16(a1, b1, a, 0, 0, 0);
            acc[ni] = a;
        }
        // LIF + scatter into own wave's 16-row LDS stripe (swizzled)
        #pragma unroll
        for (int ni = 0; ni < 4; ++ni)
            #pragma unroll
            for (int r = 0; r < 4; ++r) {
                const float y = 0.125f * acc[ni][r];    // exact
                float vv = vst[ni][r];
                vv = vv + (y - vv) * 0.5f;
                const float s = (vv >= 0.5f) ? 1.0f : 0.0f;
                vst[ni][r] = (s != 0.0f) ? 0.0f : vv;
                const int row = wv * 16 + lk * 4 + r;
                const int colb = (ni * 16 + lr) * 2;
                *(_Float16*)(ot + row * 128 + (colb ^ ((row & 7) << 4))) = (_Float16)s;
            }
        // gather h8 from own stripe + packed coalesced store
        const int rt = b * 32 + nt * 4 + wv;
        #pragma unroll
        for (int ks1 = 0; ks1 < 2; ++ks1) {
            const int row = wv * 16 + lr;
            const int colb = ks1 * 64 + lk * 16;
            const h8 vvv = *reinterpret_cast<const h8*>(ot + row * 128 + (colb ^ ((row & 7) << 4)));
            *reinterpret_cast<h8*>(osp +
                ((((size_t)rt * 4 + t) * 16 + h * 2 + ks1) * 64 + lane) * 8) = vvv;
        }
    }
}

extern "C" void kernel_launch(void* const* d_in, const int* in_sizes, int n_in,
                              void* d_out, int out_size, void* d_ws, size_t ws_size,
                              hipStream_t stream)
{
    const float* x = (const float*)d_in[0];
    const float *W[4], *bia[4], *gam[4], *bet[4], *mea[4], *rva[4];
    for (int br = 0; br < 4; ++br) {
        W[br]   = (const float*)d_in[1 + 6 * br + 0];
        bia[br] = (const float*)d_in[1 + 6 * br + 1];
        gam[br] = (const float*)d_in[1 + 6 * br + 2];
        bet[br] = (const float*)d_in[1 + 6 * br + 3];
        mea[br] = (const float*)d_in[1 + 6 * br + 4];
        rva[br] = (const float*)d_in[1 + 6 * br + 5];
    }
    char* ws = (char*)d_ws;
    _Float16* x1 = (_Float16*)(ws + 0);
    _Float16* x2 = (_Float16*)(ws + 16777216);
    _Float16* sq = (_Float16*)(ws + 33554432);
    _Float16* sk = (_Float16*)(ws + 50331648);
    _Float16* sv = (_Float16*)(ws + 67108864);
    _Float16* w1[4], *w2[4];
    for (int br = 0; br < 4; ++br) {
        w1[br] = (_Float16*)(ws + 83886080 + (size_t)br * 1048576);
        w2[br] = (_Float16*)(ws + 83886080 + (size_t)br * 1048576 + 524288);
    }
    _Float16* kvT = (_Float16*)(ws + 16777216);  // aliases x2 (dead after gemm3)
    _Float16* osp = (_Float16*)(ws + 0);         // aliases x1 (dead after gemm3)

    dim3 blk(256);
    split_pack_x<<<dim3(4096), blk, 0, stream>>>(x, x1, x2);
    pack_w_all<<<dim3(512), blk, 0, stream>>>(W[0], W[1], W[2], W[3],
        w1[0], w2[0], w1[1], w2[1], w1[2], w2[2], w1[3], w2[3]);

    gemm3_bn_lif<<<dim3(512, 3), dim3(512), 0, stream>>>(x1, x2,
        w1[0], w2[0], w1[1], w2[1], w1[2], w2[2],
        bia[0], gam[0], bet[0], mea[0], rva[0],
        bia[1], gam[1], bet[1], mea[1], rva[1],
        bia[2], gam[2], bet[2], mea[2], rva[2],
        sq, sk, sv);

    ktv_kernel<<<dim3(T_ * B_ * H_), blk, 0, stream>>>(sk, sv, kvT);
    qkv_mfma_lif<<<dim3(N_ / 64, B_, H_), blk, 0, stream>>>(sq, kvT, osp);

    gemm_p_bn_lif<<<dim3(512), dim3(512), 0, stream>>>(osp, w1[3], w2[3],
        bia[3], gam[3], bet[3], mea[3], rva[3], (float*)d_out);
}